// Round 4
// baseline (455.643 us; speedup 1.0000x reference)
//
#include <hip/hip_runtime.h>
#include <hip/hip_bf16.h>

using bf16_t = __hip_bfloat16;
typedef __attribute__((ext_vector_type(8))) __bf16 bfrag;   // 8 bf16 = 4 VGPR (MFMA A/B operand)
typedef __attribute__((ext_vector_type(4))) float f32x4;    // MFMA C/D operand

#define MFMA16(a, b, c) __builtin_amdgcn_mfma_f32_16x16x32_bf16((a), (b), (c), 0, 0, 0)

__device__ __forceinline__ void gload_lds16(const void* g, void* l) {
  // async global->LDS, 16B/lane; LDS dest = wave-uniform base + lane*16
  __builtin_amdgcn_global_load_lds((const __attribute__((address_space(1))) void*)g,
                                   (__attribute__((address_space(3))) void*)l, 16, 0, 0);
}

// ---------- weight transpose + f32->bf16 convert: in[K][N] f32 -> out[N][K] bf16 ----------
__global__ __launch_bounds__(256) void transpose_cvt(const float* __restrict__ in,
    bf16_t* __restrict__ out, int K, int N) {
  __shared__ float t[32][33];
  const int n0 = blockIdx.x * 32, k0 = blockIdx.y * 32;
  const int tx = threadIdx.x & 31, ty = threadIdx.x >> 5;   // 32 x 8
#pragma unroll
  for (int i = 0; i < 4; ++i)
    t[ty + i * 8][tx] = in[(size_t)(k0 + ty + i * 8) * N + n0 + tx];
  __syncthreads();
#pragma unroll
  for (int i = 0; i < 4; ++i)
    out[(size_t)(n0 + ty + i * 8) * K + k0 + tx] = bf16_t(t[tx][ty + i * 8]);
}

// ---------- LayerNorm: x f32 [2048][2048] -> h bf16 ----------
__global__ __launch_bounds__(256) void ln_kernel(const float* __restrict__ x,
    const float* __restrict__ sc, const float* __restrict__ of, bf16_t* __restrict__ h) {
  __shared__ float red[8];
  const int n = blockIdx.x, tid = threadIdx.x;
  const float* xr = x + (size_t)n * 2048;
  float4 a = ((const float4*)xr)[tid * 2];
  float4 b = ((const float4*)xr)[tid * 2 + 1];
  float s = a.x + a.y + a.z + a.w + b.x + b.y + b.z + b.w;
  float q = a.x * a.x + a.y * a.y + a.z * a.z + a.w * a.w +
            b.x * b.x + b.y * b.y + b.z * b.z + b.w * b.w;
#pragma unroll
  for (int m = 32; m; m >>= 1) { s += __shfl_xor(s, m); q += __shfl_xor(q, m); }
  if ((tid & 63) == 0) { red[(tid >> 6) * 2] = s; red[(tid >> 6) * 2 + 1] = q; }
  __syncthreads();
  s = red[0] + red[2] + red[4] + red[6];
  q = red[1] + red[3] + red[5] + red[7];
  const float mu = s * (1.f / 2048.f);
  const float inv = rsqrtf(q * (1.f / 2048.f) - mu * mu + 1e-5f);
  const int base = tid * 8;
  float v[8] = {a.x, a.y, a.z, a.w, b.x, b.y, b.z, b.w};
  bf16_t* hr = h + (size_t)n * 2048 + base;
#pragma unroll
  for (int j = 0; j < 8; ++j) hr[j] = bf16_t((v[j] - mu) * inv * sc[base + j] + of[base + j]);
}

// ---------- pipelined 256x256 GEMM: C = A[M][lda](bf16) * BT[N][ldb]^T ----------
// 4 windows/K-tile; window = [reads(next phase); lgkm(R); bar; stage; MFMA; vmcnt; bar]
// EPI bits: 1=+bias[col], 2=gelu(tanh), 8=store bf16 to Cb (else f32 to Cf)
template <int EPI>
__global__ __launch_bounds__(512, 2) void gemm8p(
    const bf16_t* __restrict__ A, int lda, const bf16_t* __restrict__ BT, int ldb,
    const float* __restrict__ bias, float* __restrict__ Cf, bf16_t* __restrict__ Cb,
    int M, int N, int K, size_t splitStride) {
  extern __shared__ __align__(16) char lds[];   // 128 KiB: A slots [0,64K), B slots [64K,128K)
  const int tid = threadIdx.x, wid = tid >> 6, lane = tid & 63;
  const int lc = lane & 15, lg = lane >> 4;
  // XCD-bijective blockIdx swizzle (all launches have nwg % 8 == 0)
  const int nwg = gridDim.x * gridDim.y;
  const int orig = blockIdx.y * gridDim.x + blockIdx.x;
  const int wg = (orig & 7) * (nwg >> 3) + (orig >> 3);
  const int bm = (wg / gridDim.x) * 256, bn = (wg % gridDim.x) * 256;
  const int wr = wid >> 2, wc = wid & 3;              // 2 (M) x 4 (N) waves, 128x64 out each
  const int NT = K >> 6;                              // K-tiles of 64
  // staging: linear LDS o = j*8192 + wid*1024 + lane*16 -> row=o>>6, chunk=(o>>4)&3
  const int sr = wid * 16 + (lane >> 2);              // row (j=0); j=1 -> +128
  const int lgp = (lane & 3) ^ ((sr >> 1) & 3);       // pre-swizzled global k-chunk
  const size_t rA = (size_t)128 * lda, rB = (size_t)128 * ldb;
  const bf16_t* pA0 = A + (size_t)blockIdx.z * K + (size_t)(bm + sr) * lda + lgp * 8;
  const bf16_t* pA1 = pA0 + 32;
  const bf16_t* pB0 = BT + (size_t)blockIdx.z * K + (size_t)(bn + sr) * ldb + lgp * 8;
  const bf16_t* pB1 = pB0 + 32;
  auto stA0 = [&](int ts) { char* b = lds + (((ts & 1) * 2 + 0) << 14) + wid * 1024;
    gload_lds16(pA0, b); gload_lds16(pA0 + rA, b + 8192); pA0 += 64; };
  auto stA1 = [&](int ts) { char* b = lds + (((ts & 1) * 2 + 1) << 14) + wid * 1024;
    gload_lds16(pA1, b); gload_lds16(pA1 + rA, b + 8192); pA1 += 64; };
  auto stB0 = [&](int ts) { char* b = lds + 65536 + (((ts & 1) * 2 + 0) << 14) + wid * 1024;
    gload_lds16(pB0, b); gload_lds16(pB0 + rB, b + 8192); pB0 += 64; };
  auto stB1 = [&](int ts) { char* b = lds + 65536 + (((ts & 1) * 2 + 1) << 14) + wid * 1024;
    gload_lds16(pB1, b); gload_lds16(pB1 + rB, b + 8192); pB1 += 64; };

  // prologue: tile0 {A-k0,B-k0,A-k1,B-k1}, tile1 {A-k0,B-k0,A-k1}
  stA0(0); stB0(0); stA1(0); stB1(0); stA0(1); stB0(1); stA1(1);
  asm volatile("s_waitcnt vmcnt(10)" ::: "memory");   // tile0 A-k0,B-k0 landed (per-wave)
  __builtin_amdgcn_s_barrier();                       // -> landed for all waves

// swizzled fragment read: logical (row, lg-chunk) of a [256 rows][32 k] slot
#define FR(off, row) \
  (*(const bfrag*)(lds + (off) + (row) * 64 + ((lg ^ (((row) >> 1) & 3)) << 4)))

  f32x4 acc[8][4] = {};
  bfrag a0[4], a1v[4], a2v[4], a3v[4], bA[4], bB[4];
#pragma unroll
  for (int m = 0; m < 4; ++m) a0[m] = FR(0, wr * 128 + m * 16 + lc);
#pragma unroll
  for (int n = 0; n < 4; ++n) bA[n] = FR(65536, wc * 64 + n * 16 + lc);

#pragma unroll 2
  for (int t = 0; t < NT; ++t) {
    const int d = t & 1;
    const int aoff0 = (d * 2 + 0) << 14, aoff1 = (d * 2 + 1) << 14;
    const int boff0 = 65536 + aoff0, boff1 = 65536 + aoff1;
    const int an0 = ((d ^ 1) * 2) << 14, bn0 = 65536 + an0;   // next tile kk0 slots
    // ---- W0: prefetch a(m4-7,kk0); MFMA P0 = m0-3 x n0-3 @kk0
    {
#pragma unroll
      for (int m = 0; m < 4; ++m) a1v[m] = FR(aoff0, wr * 128 + (4 + m) * 16 + lc);
      asm volatile("s_waitcnt lgkmcnt(4)" ::: "memory");
      __builtin_amdgcn_sched_barrier(0);
      __builtin_amdgcn_s_barrier();
      if (t + 1 < NT) stB1(t + 1);
      __builtin_amdgcn_s_setprio(1);
#pragma unroll
      for (int m = 0; m < 4; ++m)
#pragma unroll
        for (int n = 0; n < 4; ++n) acc[m][n] = MFMA16(a0[m], bA[n], acc[m][n]);
      __builtin_amdgcn_s_setprio(0);
      if (t < NT - 2) asm volatile("s_waitcnt vmcnt(8)" ::: "memory");
      else            asm volatile("s_waitcnt vmcnt(0)" ::: "memory");
      __builtin_amdgcn_s_barrier();
    }
    // ---- W1: prefetch a(m0-3,kk1)+b(n0-3,kk1); MFMA P1 = m4-7 x n0-3 @kk0
    {
#pragma unroll
      for (int m = 0; m < 4; ++m) a2v[m] = FR(aoff1, wr * 128 + m * 16 + lc);
#pragma unroll
      for (int n = 0; n < 4; ++n) bB[n] = FR(boff1, wc * 64 + n * 16 + lc);
      asm volatile("s_waitcnt lgkmcnt(8)" ::: "memory");
      __builtin_amdgcn_sched_barrier(0);
      __builtin_amdgcn_s_barrier();
      if (t + 2 < NT) stA0(t + 2);
      __builtin_amdgcn_s_setprio(1);
#pragma unroll
      for (int m = 0; m < 4; ++m)
#pragma unroll
        for (int n = 0; n < 4; ++n) acc[4 + m][n] = MFMA16(a1v[m], bA[n], acc[4 + m][n]);
      __builtin_amdgcn_s_setprio(0);
      if (t < NT - 2) asm volatile("s_waitcnt vmcnt(8)" ::: "memory");
      else            asm volatile("s_waitcnt vmcnt(0)" ::: "memory");
      __builtin_amdgcn_s_barrier();
    }
    // ---- W2: prefetch a(m4-7,kk1); MFMA P2 = m0-3 x n0-3 @kk1
    {
#pragma unroll
      for (int m = 0; m < 4; ++m) a3v[m] = FR(aoff1, wr * 128 + (4 + m) * 16 + lc);
      asm volatile("s_waitcnt lgkmcnt(4)" ::: "memory");
      __builtin_amdgcn_sched_barrier(0);
      __builtin_amdgcn_s_barrier();
      if (t + 2 < NT) stB0(t + 2);
      __builtin_amdgcn_s_setprio(1);
#pragma unroll
      for (int m = 0; m < 4; ++m)
#pragma unroll
        for (int n = 0; n < 4; ++n) acc[m][n] = MFMA16(a2v[m], bB[n], acc[m][n]);
      __builtin_amdgcn_s_setprio(0);
      if (t < NT - 2) asm volatile("s_waitcnt vmcnt(8)" ::: "memory");
      else            asm volatile("s_waitcnt vmcnt(0)" ::: "memory");
      __builtin_amdgcn_s_barrier();
    }
    // ---- W3: prefetch next tile a(m0-3,kk0)+b(n0-3,kk0); MFMA P3 = m4-7 x n0-3 @kk1
    {
      if (t + 1 < NT) {
#pragma unroll
        for (int m = 0; m < 4; ++m) a0[m] = FR(an0, wr * 128 + m * 16 + lc);
#pragma unroll
        for (int n = 0; n < 4; ++n) bA[n] = FR(bn0, wc * 64 + n * 16 + lc);
        asm volatile("s_waitcnt lgkmcnt(8)" ::: "memory");
      } else {
        asm volatile("s_waitcnt lgkmcnt(0)" ::: "memory");
      }
      __builtin_amdgcn_sched_barrier(0);
      __builtin_amdgcn_s_barrier();
      if (t + 2 < NT) stA1(t + 2);
      __builtin_amdgcn_s_setprio(1);
#pragma unroll
      for (int m = 0; m < 4; ++m)
#pragma unroll
        for (int n = 0; n < 4; ++n) acc[4 + m][n] = MFMA16(a3v[m], bB[n], acc[4 + m][n]);
      __builtin_amdgcn_s_setprio(0);
      if (t < NT - 2) asm volatile("s_waitcnt vmcnt(8)" ::: "memory");
      else            asm volatile("s_waitcnt vmcnt(0)" ::: "memory");
      __builtin_amdgcn_s_barrier();
    }
  }
#undef FR
  // ---- epilogue
  float* Cfz = Cf + (size_t)blockIdx.z * splitStride;
  const int row0 = bm + wr * 128 + lg * 4;
  const int col0 = bn + wc * 64 + lc;
#pragma unroll
  for (int m = 0; m < 8; ++m) {
#pragma unroll
    for (int n = 0; n < 4; ++n) {
      const int col = col0 + n * 16;
      float bv = (EPI & 1) ? bias[col] : 0.f;
#pragma unroll
      for (int i = 0; i < 4; ++i) {
        const int row = row0 + m * 16 + i;
        float v = acc[m][n][i];
        if (EPI & 1) v += bv;
        if (EPI & 2) v = 0.5f * v * (1.f + tanhf(0.7978845608028654f * (v + 0.044715f * v * v * v)));
        if (EPI & 8) Cb[(size_t)row * N + col] = bf16_t(v);
        else         Cfz[(size_t)row * N + col] = v;
      }
    }
  }
}

// ---------- split-K partial reduction ----------
template <int NP, bool ADDIN, bool BIAS>
__global__ __launch_bounds__(256) void reduceP(const float* __restrict__ p0,
    const float* __restrict__ p1, const float* __restrict__ p2,
    const float* __restrict__ p3, const float* __restrict__ bias,
    float* __restrict__ out, int total, int colmask) {
  const int i = (blockIdx.x * 256 + threadIdx.x) * 4;
  if (i >= total) return;
  float4 v = *(const float4*)(p0 + i);
  float4 w = *(const float4*)(p1 + i);
  v.x += w.x; v.y += w.y; v.z += w.z; v.w += w.w;
  if (NP == 4) {
    float4 u = *(const float4*)(p2 + i);
    float4 z = *(const float4*)(p3 + i);
    v.x += u.x + z.x; v.y += u.y + z.y; v.z += u.z + z.z; v.w += u.w + z.w;
  }
  if (BIAS) {
    float4 b = *(const float4*)(bias + (i & colmask));
    v.x += b.x; v.y += b.y; v.z += b.z; v.w += b.w;
  }
  if (ADDIN) {
    float4 o = *(const float4*)(out + i);
    v.x += o.x; v.y += o.y; v.z += o.z; v.w += o.w;
  }
  *(float4*)(out + i) = v;
}

// ---------- RoPE + head split ----------
__global__ __launch_bounds__(128) void rope_kernel(const bf16_t* __restrict__ qkv,
    bf16_t* __restrict__ qh, bf16_t* __restrict__ kh, bf16_t* __restrict__ vT) {
  const int n = blockIdx.x, hh = blockIdx.y;
  const int d = threadIdx.x;
  const int mp = hh >> 2, hi = hh & 3;
  const bf16_t* row = qkv + (size_t)n * 6144 + mp * 1536 + hi * 128;  // [q|v|k] each 512 per mp
  float q = __bfloat162float(row[d]);
  float k = __bfloat162float(row[1024 + d]);
  if (d < 64) {  // wave-uniform branch
    const float ang = (float)n * powf(10000.f, -(float)(d & ~1) / 64.f);
    const float sn = sinf(ang), cs = cosf(ang);
    const float qp = __shfl_xor(q, 1), kp = __shfl_xor(k, 1);
    if (d & 1) { q = q * cs + qp * sn; k = k * cs + kp * sn; }
    else       { q = q * cs - qp * sn; k = k * cs - kp * sn; }
  }
  qh[((size_t)hh * 2048 + n) * 128 + d] = bf16_t(q * 0.08838834764831845f); // 1/sqrt(128)
  kh[((size_t)hh * 2048 + n) * 128 + d] = bf16_t(k);
  vT[((size_t)hh * 128 + d) * 2048 + n] = row[512 + d];
}

// ---------- causal flash attention, load-balanced pairs + swizzled dbuf LDS ----------
__global__ __launch_bounds__(256) void attn_kernel(const bf16_t* __restrict__ qh,
    const bf16_t* __restrict__ kh, const bf16_t* __restrict__ vT, bf16_t* __restrict__ av) {
  __shared__ alignas(16) char Kbuf[2][16384];    // [kv 64][d 128] bf16, chunk ^= row&15
  __shared__ alignas(16) char Vbuf[2][16384];    // [d 128][kv 64] bf16, chunk ^= row&7
  __shared__ alignas(16) bf16_t Ps[4][16 * 72];  // per-wave P, stride 72 (144B rows)
  const int p = blockIdx.x, h = blockIdx.y;
  const int tid = threadIdx.x, wid = tid >> 6, lane = tid & 63;
  const int lc = lane & 15, lg = lane >> 4;
  const int krow = wid * 4 + (lane >> 4);        // + i*16 ; stored chunk = lane&15
  const int vrow = wid * 8 + (lane >> 3);        // + i*32 ; stored chunk = lane&7

  auto stage = [&](int kv0, int d) {
#pragma unroll
    for (int i = 0; i < 4; ++i) {
      const int kr = i * 16 + krow;
      const int kch = (lane & 15) ^ (kr & 15);   // pre-swizzled global chunk
      gload_lds16(kh + ((size_t)h * 2048 + kv0 + kr) * 128 + kch * 8,
                  Kbuf[d] + i * 4096 + wid * 1024);
      const int vr = i * 32 + vrow;
      const int vch = (lane & 7) ^ (vr & 7);
      gload_lds16(vT + ((size_t)h * 128 + vr) * 2048 + kv0 + vch * 8,
                  Vbuf[d] + i * 4096 + wid * 1024);
    }
  };
#define FRK(d, row, ch) (*(const bfrag*)(Kbuf[d] + (row) * 256 + (((ch) ^ ((row) & 15)) << 4)))
#define FRV(d, row, ch) (*(const bfrag*)(Vbuf[d] + (row) * 128 + (((ch) ^ ((row) & 7)) << 4)))

#pragma unroll 1
  for (int half = 0; half < 2; ++half) {
    const int qt = half ? (31 - p) : p;
    const int nkv = qt + 1;
    const int qr = qt * 64 + wid * 16;
    const bf16_t* Qb = qh + ((size_t)h * 2048 + qr) * 128;
    bfrag qf[4];
#pragma unroll
    for (int ks = 0; ks < 4; ++ks)
      qf[ks] = *(const bfrag*)&Qb[lc * 128 + ks * 32 + lg * 8];
    f32x4 O[8] = {};
    float mr[4] = {-1e30f, -1e30f, -1e30f, -1e30f};
    float lsum[4] = {0.f, 0.f, 0.f, 0.f};

    stage(0, 0);
    asm volatile("s_waitcnt vmcnt(0)" ::: "memory");
    __builtin_amdgcn_s_barrier();

#pragma unroll 1
    for (int kt = 0; kt < nkv; ++kt) {
      const int d = kt & 1;
      const int kv0 = kt * 64;
      if (kt + 1 < nkv) stage(kv0 + 64, d ^ 1);  // overlap with compute
      f32x4 s[4];
#pragma unroll
      for (int c = 0; c < 4; ++c) {
        f32x4 a = {};
#pragma unroll
        for (int ks = 0; ks < 4; ++ks) {
          bfrag kf = FRK(d, c * 16 + lc, ks * 4 + lg);
          a = MFMA16(qf[ks], kf, a);
        }
        s[c] = a;
      }
      if (kt == qt) {  // diagonal tile: causal mask
#pragma unroll
        for (int c = 0; c < 4; ++c)
#pragma unroll
          for (int i = 0; i < 4; ++i)
            if (kv0 + c * 16 + lc > qr + lg * 4 + i) s[c][i] = -1e10f;
      }
      float pm[4];
#pragma unroll
      for (int i = 0; i < 4; ++i)
        pm[i] = fmaxf(fmaxf(s[0][i], s[1][i]), fmaxf(s[2][i], s[3][i]));
#pragma unroll
      for (int m = 1; m < 16; m <<= 1)
#pragma unroll
        for (int i = 0; i < 4; ++i) pm[i] = fmaxf(pm[i], __shfl_xor(pm[i], m));
      float al[4], rs[4];
#pragma unroll
      for (int i = 0; i < 4; ++i) {
        const float mn = fmaxf(mr[i], pm[i]);
        al[i] = __expf(mr[i] - mn);
        mr[i] = mn;
        rs[i] = 0.f;
      }
#pragma unroll
      for (int c = 0; c < 4; ++c)
#pragma unroll
        for (int i = 0; i < 4; ++i) {
          const float pv = __expf(s[c][i] - mr[i]);
          s[c][i] = pv; rs[i] += pv;
        }
#pragma unroll
      for (int m = 1; m < 16; m <<= 1)
#pragma unroll
        for (int i = 0; i < 4; ++i) rs[i] += __shfl_xor(rs[i], m);
#pragma unroll
      for (int i = 0; i < 4; ++i) lsum[i] = lsum[i] * al[i] + rs[i];
#pragma unroll
      for (int n = 0; n < 8; ++n)
#pragma unroll
        for (int i = 0; i < 4; ++i) O[n][i] *= al[i];
#pragma unroll
      for (int c = 0; c < 4; ++c)
#pragma unroll
        for (int i = 0; i < 4; ++i)
          Ps[wid][(lg * 4 + i) * 72 + c * 16 + lc] = bf16_t(s[c][i]);
#pragma unroll
      for (int k2 = 0; k2 < 2; ++k2) {
        bfrag pf = *(const bfrag*)((const char*)&Ps[wid][0] + lc * 144 + k2 * 64 + lg * 16);
#pragma unroll
        for (int n = 0; n < 8; ++n) {
          bfrag vf = FRV(d, n * 16 + lc, k2 * 4 + lg);
          O[n] = MFMA16(pf, vf, O[n]);
        }
      }
      if (kt + 1 < nkv) asm volatile("s_waitcnt vmcnt(0)" ::: "memory");  // next tile landed
      asm volatile("s_waitcnt lgkmcnt(0)" ::: "memory");
      __builtin_amdgcn_s_barrier();
    }
#pragma unroll
    for (int n = 0; n < 8; ++n)
#pragma unroll
      for (int i = 0; i < 4; ++i)
        av[(size_t)(qr + lg * 4 + i) * 2048 + h * 128 + n * 16 + lc] = bf16_t(O[n][i] / lsum[i]);
    __builtin_amdgcn_s_barrier();  // all waves done before next half re-stages buf0
  }
#undef FRK
#undef FRV
}

extern "C" void kernel_launch(void* const* d_in, const int* in_sizes, int n_in,
                              void* d_out, int out_size, void* d_ws, size_t ws_size,
                              hipStream_t stream) {
  const float* x        = (const float*)d_in[0];
  const float* ln_scale = (const float*)d_in[1];
  const float* ln_offset= (const float*)d_in[2];
  const float* w_qkv    = (const float*)d_in[3];   // [2048][6144]
  const float* w_ao     = (const float*)d_in[4];   // [2048][2048]
  const float* w_ff_in  = (const float*)d_in[5];   // [2048][8192]
  const float* b_ff_in  = (const float*)d_in[6];   // [8192]
  const float* w_ff_out = (const float*)d_in[7];   // [8192][2048]
  const float* b_ff_out = (const float*)d_in[8];   // [2048]
  float* out = (float*)d_out;

  char* ws = (char*)d_ws;
  bf16_t* wqkvT   = (bf16_t*)(ws);                  // [6144][2048]  (dead after qkv GEMM)
  bf16_t* waoT    = (bf16_t*)(ws + 25165824);       // [2048][2048]
  bf16_t* wffinT  = (bf16_t*)(ws + 33554432);       // [8192][2048]
  bf16_t* wffoutT = (bf16_t*)(ws + 67108864);       // [2048][8192]
  bf16_t* h       = (bf16_t*)(ws + 100663296);      // [2048][2048]
  bf16_t* qhb     = (bf16_t*)(ws + 109051904);      // [16][2048][128]
  bf16_t* khb     = (bf16_t*)(ws + 117440512);
  bf16_t* vTb     = (bf16_t*)(ws + 125829120);      // [16][128][2048]
  bf16_t* avb     = (bf16_t*)(ws + 134217728);      // [2048][2048]
  bf16_t* qkvb    = (bf16_t*)(ws + 142606336);      // [2048][6144]; later ff1 [2048][8192]
  bf16_t* ff1b    = qkvb;
  float*  pa      = (float*)(ws + 142606336);       // attn_out partials (over dead qkvb)
  float*  pf      = (float*)(ws);                   // ff_out partials (over dead weights)

  hipFuncSetAttribute((const void*)gemm8p<0>,  hipFuncAttributeMaxDynamicSharedMemorySize, 131072);
  hipFuncSetAttribute((const void*)gemm8p<8>,  hipFuncAttributeMaxDynamicSharedMemorySize, 131072);
  hipFuncSetAttribute((const void*)gemm8p<11>, hipFuncAttributeMaxDynamicSharedMemorySize, 131072);

  dim3 b256(256), b512(512);
  transpose_cvt<<<dim3(192, 64),  b256, 0, stream>>>(w_qkv,    wqkvT,   2048, 6144);
  transpose_cvt<<<dim3(64, 64),   b256, 0, stream>>>(w_ao,     waoT,    2048, 2048);
  transpose_cvt<<<dim3(256, 64),  b256, 0, stream>>>(w_ff_in,  wffinT,  2048, 8192);
  transpose_cvt<<<dim3(64, 256),  b256, 0, stream>>>(w_ff_out, wffoutT, 8192, 2048);
  ln_kernel<<<dim3(2048), b256, 0, stream>>>(x, ln_scale, ln_offset, h);

  gemm8p<8><<<dim3(24, 8, 1), b512, 131072, stream>>>(h, 2048, wqkvT, 2048,
      nullptr, nullptr, qkvb, 2048, 6144, 2048, 0);
  rope_kernel<<<dim3(2048, 16), dim3(128), 0, stream>>>(qkvb, qhb, khb, vTb);
  attn_kernel<<<dim3(16, 16), b256, 0, stream>>>(qhb, khb, vTb, avb);

  // attn_out: split-K=2 (K=1024 each)
  gemm8p<0><<<dim3(8, 8, 2), b512, 131072, stream>>>(avb, 2048, waoT, 2048,
      nullptr, pa, nullptr, 2048, 2048, 1024, (size_t)2048 * 2048);
  reduceP<2, false, false><<<dim3(4096), b256, 0, stream>>>(pa, pa + 4194304,
      nullptr, nullptr, nullptr, out, 4194304, 2047);

  gemm8p<11><<<dim3(32, 8, 1), b512, 131072, stream>>>(h, 2048, wffinT, 2048,
      b_ff_in, nullptr, ff1b, 2048, 8192, 2048, 0);

  // ff_out: split-K=4 (K=2048 each)
  gemm8p<0><<<dim3(8, 8, 4), b512, 131072, stream>>>(ff1b, 8192, wffoutT, 8192,
      nullptr, pf, nullptr, 2048, 2048, 2048, (size_t)2048 * 2048);
  reduceP<4, true, true><<<dim3(4096), b256, 0, stream>>>(pf, pf + 4194304,
      pf + 2 * 4194304, pf + 3 * 4194304, b_ff_out, out, 4194304, 2047);
}

// Round 5
// 452.189 us; speedup vs baseline: 1.0076x; 1.0076x over previous
//
#include <hip/hip_runtime.h>
#include <hip/hip_bf16.h>

using bf16_t = __hip_bfloat16;
typedef __attribute__((ext_vector_type(8))) __bf16 bfrag;   // 8 bf16 = 4 VGPR (MFMA A/B operand)
typedef __attribute__((ext_vector_type(4))) float f32x4;    // MFMA C/D operand

#define MFMA16(a, b, c) __builtin_amdgcn_mfma_f32_16x16x32_bf16((a), (b), (c), 0, 0, 0)

__device__ __forceinline__ void gload_lds16(const void* g, void* l) {
  // async global->LDS, 16B/lane; LDS dest = wave-uniform base + lane*16
  __builtin_amdgcn_global_load_lds((const __attribute__((address_space(1))) void*)g,
                                   (__attribute__((address_space(3))) void*)l, 16, 0, 0);
}

// ---------- weight transpose + f32->bf16 convert: in[K][N] f32 -> out[N][K] bf16 ----------
__global__ __launch_bounds__(256) void transpose_cvt(const float* __restrict__ in,
    bf16_t* __restrict__ out, int K, int N) {
  __shared__ float t[32][33];
  const int n0 = blockIdx.x * 32, k0 = blockIdx.y * 32;
  const int tx = threadIdx.x & 31, ty = threadIdx.x >> 5;   // 32 x 8
#pragma unroll
  for (int i = 0; i < 4; ++i)
    t[ty + i * 8][tx] = in[(size_t)(k0 + ty + i * 8) * N + n0 + tx];
  __syncthreads();
#pragma unroll
  for (int i = 0; i < 4; ++i)
    out[(size_t)(n0 + ty + i * 8) * K + k0 + tx] = bf16_t(t[tx][ty + i * 8]);
}

// ---------- LayerNorm: x f32 [2048][2048] -> h bf16 ----------
__global__ __launch_bounds__(256) void ln_kernel(const float* __restrict__ x,
    const float* __restrict__ sc, const float* __restrict__ of, bf16_t* __restrict__ h) {
  __shared__ float red[8];
  const int n = blockIdx.x, tid = threadIdx.x;
  const float* xr = x + (size_t)n * 2048;
  float4 a = ((const float4*)xr)[tid * 2];
  float4 b = ((const float4*)xr)[tid * 2 + 1];
  float s = a.x + a.y + a.z + a.w + b.x + b.y + b.z + b.w;
  float q = a.x * a.x + a.y * a.y + a.z * a.z + a.w * a.w +
            b.x * b.x + b.y * b.y + b.z * b.z + b.w * b.w;
#pragma unroll
  for (int m = 32; m; m >>= 1) { s += __shfl_xor(s, m); q += __shfl_xor(q, m); }
  if ((tid & 63) == 0) { red[(tid >> 6) * 2] = s; red[(tid >> 6) * 2 + 1] = q; }
  __syncthreads();
  s = red[0] + red[2] + red[4] + red[6];
  q = red[1] + red[3] + red[5] + red[7];
  const float mu = s * (1.f / 2048.f);
  const float inv = rsqrtf(q * (1.f / 2048.f) - mu * mu + 1e-5f);
  const int base = tid * 8;
  float v[8] = {a.x, a.y, a.z, a.w, b.x, b.y, b.z, b.w};
  bf16_t* hr = h + (size_t)n * 2048 + base;
#pragma unroll
  for (int j = 0; j < 8; ++j) hr[j] = bf16_t((v[j] - mu) * inv * sc[base + j] + of[base + j]);
}

// ---------- 8-phase 256x256 GEMM (round-3 schedule) + LDS-staged vector epilogue ----------
// EPI bits: 1=+bias[col], 2=gelu(tanh), 8=store bf16 to Cb (else f32 to Cf)
template <int EPI>
__global__ __launch_bounds__(512, 2) void gemm8p(
    const bf16_t* __restrict__ A, int lda, const bf16_t* __restrict__ BT, int ldb,
    const float* __restrict__ bias, float* __restrict__ Cf, bf16_t* __restrict__ Cb,
    int M, int N, int K, size_t splitStride) {
  extern __shared__ __align__(16) char lds[];   // 128 KiB: A slots [0,64K), B slots [64K,128K)
  const int tid = threadIdx.x, wid = tid >> 6, lane = tid & 63;
  const int lc = lane & 15, lg = lane >> 4;
  const int bm = blockIdx.y * 256, bn = blockIdx.x * 256;
  const int wr = wid >> 2, wc = wid & 3;              // 2 (M) x 4 (N) waves, each 128x64 out
  const int NT = K >> 6;                              // K-tiles of 64
  // staging: linear LDS o = j*8192 + wid*1024 + lane*16 -> row=o>>6, chunk=(o>>4)&3
  const int sr = wid * 16 + (lane >> 2);              // row (j=0); j=1 -> +128
  const int lgp = (lane & 3) ^ ((sr >> 1) & 3);       // pre-swizzled global k-chunk
  const size_t rA = (size_t)128 * lda, rB = (size_t)128 * ldb;
  const bf16_t* pA0 = A + (size_t)blockIdx.z * K + (size_t)(bm + sr) * lda + lgp * 8;
  const bf16_t* pA1 = pA0 + 32;
  const bf16_t* pB0 = BT + (size_t)blockIdx.z * K + (size_t)(bn + sr) * ldb + lgp * 8;
  const bf16_t* pB1 = pB0 + 32;
  // each stX stages one half-tile (2 gload instrs); slot parity = ts&1
  auto stA0 = [&](int ts) { char* b = lds + (((ts & 1) * 2 + 0) << 14) + wid * 1024;
    gload_lds16(pA0, b); gload_lds16(pA0 + rA, b + 8192); pA0 += 64; };
  auto stA1 = [&](int ts) { char* b = lds + (((ts & 1) * 2 + 1) << 14) + wid * 1024;
    gload_lds16(pA1, b); gload_lds16(pA1 + rA, b + 8192); pA1 += 64; };
  auto stB0 = [&](int ts) { char* b = lds + 65536 + (((ts & 1) * 2 + 0) << 14) + wid * 1024;
    gload_lds16(pB0, b); gload_lds16(pB0 + rB, b + 8192); pB0 += 64; };
  auto stB1 = [&](int ts) { char* b = lds + 65536 + (((ts & 1) * 2 + 1) << 14) + wid * 1024;
    gload_lds16(pB1, b); gload_lds16(pB1 + rB, b + 8192); pB1 += 64; };

  // prologue: tile0 {A-k0,B-k0,A-k1,B-k1}, tile1 {A-k0,B-k0,A-k1}
  stA0(0); stB0(0); stA1(0); stB1(0); stA0(1); stB0(1); stA1(1);
  asm volatile("s_waitcnt vmcnt(6)" ::: "memory");    // tile0's 4 halves landed
  __builtin_amdgcn_s_barrier();

  f32x4 acc[8][4] = {};
// swizzled fragment read: logical (row, lg) of a [256 rows][32 k] slot
#define FR(off, row) \
  (*(const bfrag*)(lds + (off) + (row) * 64 + ((lg ^ (((row) >> 1) & 3)) << 4)))

  for (int t = 0; t < NT; ++t) {
    const int d = t & 1;
    const int aoff0 = (d * 2 + 0) << 14, aoff1 = (d * 2 + 1) << 14;
    const int boff0 = 65536 + aoff0, boff1 = 65536 + aoff1;
    bfrag a[8];
    // ---- phase 0: reads A-k0 frags + B-k0 n=0,1; stages (t+1).B-k1
    {
#pragma unroll
      for (int m = 0; m < 8; ++m) a[m] = FR(aoff0, wr * 128 + m * 16 + lc);
      bfrag b0 = FR(boff0, wc * 64 + lc);
      bfrag b1 = FR(boff0, wc * 64 + 16 + lc);
      if (t + 1 < NT) stB1(t + 1);
      __builtin_amdgcn_s_barrier();
      asm volatile("s_waitcnt lgkmcnt(0)" ::: "memory");
      __builtin_amdgcn_sched_barrier(0);
      __builtin_amdgcn_s_setprio(1);
#pragma unroll
      for (int m = 0; m < 8; ++m) {
        acc[m][0] = MFMA16(a[m], b0, acc[m][0]);
        acc[m][1] = MFMA16(a[m], b1, acc[m][1]);
      }
      __builtin_amdgcn_s_setprio(0);
      __builtin_amdgcn_s_barrier();
    }
    // ---- phase 1: B-k0 n=2,3; stages (t+2).A-k0
    {
      bfrag b2 = FR(boff0, wc * 64 + 32 + lc);
      bfrag b3 = FR(boff0, wc * 64 + 48 + lc);
      if (t + 2 < NT) stA0(t + 2);
      __builtin_amdgcn_s_barrier();
      asm volatile("s_waitcnt lgkmcnt(0)" ::: "memory");
      __builtin_amdgcn_sched_barrier(0);
      __builtin_amdgcn_s_setprio(1);
#pragma unroll
      for (int m = 0; m < 8; ++m) {
        acc[m][2] = MFMA16(a[m], b2, acc[m][2]);
        acc[m][3] = MFMA16(a[m], b3, acc[m][3]);
      }
      __builtin_amdgcn_s_setprio(0);
      __builtin_amdgcn_s_barrier();
    }
    // ---- phase 2: reloads a[] from A-k1; B-k1 n=0,1; stages (t+2).B-k0
    {
#pragma unroll
      for (int m = 0; m < 8; ++m) a[m] = FR(aoff1, wr * 128 + m * 16 + lc);
      bfrag b0 = FR(boff1, wc * 64 + lc);
      bfrag b1 = FR(boff1, wc * 64 + 16 + lc);
      if (t + 2 < NT) stB0(t + 2);
      __builtin_amdgcn_s_barrier();
      asm volatile("s_waitcnt lgkmcnt(0)" ::: "memory");
      __builtin_amdgcn_sched_barrier(0);
      __builtin_amdgcn_s_setprio(1);
#pragma unroll
      for (int m = 0; m < 8; ++m) {
        acc[m][0] = MFMA16(a[m], b0, acc[m][0]);
        acc[m][1] = MFMA16(a[m], b1, acc[m][1]);
      }
      __builtin_amdgcn_s_setprio(0);
      __builtin_amdgcn_s_barrier();
    }
    // ---- phase 3: B-k1 n=2,3; stages (t+2).A-k1; end-of-tile counted vmcnt
    {
      bfrag b2 = FR(boff1, wc * 64 + 32 + lc);
      bfrag b3 = FR(boff1, wc * 64 + 48 + lc);
      if (t + 2 < NT) stA1(t + 2);
      __builtin_amdgcn_s_barrier();
      asm volatile("s_waitcnt lgkmcnt(0)" ::: "memory");
      __builtin_amdgcn_sched_barrier(0);
      __builtin_amdgcn_s_setprio(1);
#pragma unroll
      for (int m = 0; m < 8; ++m) {
        acc[m][2] = MFMA16(a[m], b2, acc[m][2]);
        acc[m][3] = MFMA16(a[m], b3, acc[m][3]);
      }
      __builtin_amdgcn_s_setprio(0);
      if (t < NT - 2) asm volatile("s_waitcnt vmcnt(6)" ::: "memory");  // 3 half-stages in flight
      else            asm volatile("s_waitcnt vmcnt(0)" ::: "memory");  // epilogue drain
      __builtin_amdgcn_s_barrier();
    }
  }
#undef FR
  // ---- epilogue: per-wave LDS transpose staging -> coalesced vector stores
  char* W = lds + wid * 16384;   // 16KB private per wave; all K-loop reads drained above
  if (EPI & 8) {
    // bf16 out: 2 chunks of 4 m-values (64 rows x 64 cols), LDS tile [64][72] bf16
    bf16_t* Wb = (bf16_t*)W;
#pragma unroll
    for (int mc = 0; mc < 2; ++mc) {
#pragma unroll
      for (int m4 = 0; m4 < 4; ++m4) {
#pragma unroll
        for (int n = 0; n < 4; ++n) {
          const int col = bn + wc * 64 + n * 16 + lc;
          float bv = (EPI & 1) ? bias[col] : 0.f;
#pragma unroll
          for (int i = 0; i < 4; ++i) {
            float v = acc[mc * 4 + m4][n][i];
            if (EPI & 1) v += bv;
            if (EPI & 2) v = 0.5f * v * (1.f + tanhf(0.7978845608028654f * (v + 0.044715f * v * v * v)));
            Wb[(m4 * 16 + lg * 4 + i) * 72 + n * 16 + lc] = bf16_t(v);
          }
        }
      }
      asm volatile("s_waitcnt lgkmcnt(0)" ::: "memory");
      __builtin_amdgcn_sched_barrier(0);
#pragma unroll
      for (int p = 0; p < 8; ++p) {
        const int rl = p * 8 + (lane >> 3), j = lane & 7;
        uint4 v = *(const uint4*)&Wb[rl * 72 + j * 8];
        const int grow = bm + wr * 128 + mc * 64 + rl;
        const int gcol = bn + wc * 64 + j * 8;
        *(uint4*)&Cb[(size_t)grow * N + gcol] = v;
      }
      asm volatile("s_waitcnt lgkmcnt(0)" ::: "memory");   // reads done before next chunk writes
      __builtin_amdgcn_sched_barrier(0);
    }
  } else {
    // f32 out: 4 chunks of 2 m-values (32 rows x 64 cols), LDS tile [32][72] f32
    float* Wf = (float*)W;
    float* Cfz = Cf + (size_t)blockIdx.z * splitStride;
#pragma unroll
    for (int mc = 0; mc < 4; ++mc) {
#pragma unroll
      for (int m2 = 0; m2 < 2; ++m2) {
#pragma unroll
        for (int n = 0; n < 4; ++n) {
          const int col = bn + wc * 64 + n * 16 + lc;
          float bv = (EPI & 1) ? bias[col] : 0.f;
#pragma unroll
          for (int i = 0; i < 4; ++i) {
            float v = acc[mc * 2 + m2][n][i];
            if (EPI & 1) v += bv;
            if (EPI & 2) v = 0.5f * v * (1.f + tanhf(0.7978845608028654f * (v + 0.044715f * v * v * v)));
            Wf[(m2 * 16 + lg * 4 + i) * 72 + n * 16 + lc] = v;
          }
        }
      }
      asm volatile("s_waitcnt lgkmcnt(0)" ::: "memory");
      __builtin_amdgcn_sched_barrier(0);
#pragma unroll
      for (int p = 0; p < 8; ++p) {
        const int rl = p * 4 + (lane >> 4), j = lane & 15;
        float4 v = *(const float4*)&Wf[rl * 72 + j * 4];
        const int grow = bm + wr * 128 + mc * 32 + rl;
        const int gcol = bn + wc * 64 + j * 4;
        *(float4*)&Cfz[(size_t)grow * N + gcol] = v;
      }
      asm volatile("s_waitcnt lgkmcnt(0)" ::: "memory");
      __builtin_amdgcn_sched_barrier(0);
    }
  }
}

// ---------- split-K partial reduction ----------
template <int NP, bool ADDIN, bool BIAS>
__global__ __launch_bounds__(256) void reduceP(const float* __restrict__ p0,
    const float* __restrict__ p1, const float* __restrict__ p2,
    const float* __restrict__ p3, const float* __restrict__ bias,
    float* __restrict__ out, int total, int colmask) {
  const int i = (blockIdx.x * 256 + threadIdx.x) * 4;
  if (i >= total) return;
  float4 v = *(const float4*)(p0 + i);
  float4 w = *(const float4*)(p1 + i);
  v.x += w.x; v.y += w.y; v.z += w.z; v.w += w.w;
  if (NP == 4) {
    float4 u = *(const float4*)(p2 + i);
    float4 z = *(const float4*)(p3 + i);
    v.x += u.x + z.x; v.y += u.y + z.y; v.z += u.z + z.z; v.w += u.w + z.w;
  }
  if (BIAS) {
    float4 b = *(const float4*)(bias + (i & colmask));
    v.x += b.x; v.y += b.y; v.z += b.z; v.w += b.w;
  }
  if (ADDIN) {
    float4 o = *(const float4*)(out + i);
    v.x += o.x; v.y += o.y; v.z += o.z; v.w += o.w;
  }
  *(float4*)(out + i) = v;
}

// ---------- RoPE + head split ----------
__global__ __launch_bounds__(128) void rope_kernel(const bf16_t* __restrict__ qkv,
    bf16_t* __restrict__ qh, bf16_t* __restrict__ kh, bf16_t* __restrict__ vT) {
  const int n = blockIdx.x, hh = blockIdx.y;
  const int d = threadIdx.x;
  const int mp = hh >> 2, hi = hh & 3;
  const bf16_t* row = qkv + (size_t)n * 6144 + mp * 1536 + hi * 128;  // [q|v|k] each 512 per mp
  float q = __bfloat162float(row[d]);
  float k = __bfloat162float(row[1024 + d]);
  if (d < 64) {  // wave-uniform branch
    const float ang = (float)n * powf(10000.f, -(float)(d & ~1) / 64.f);
    const float sn = sinf(ang), cs = cosf(ang);
    const float qp = __shfl_xor(q, 1), kp = __shfl_xor(k, 1);
    if (d & 1) { q = q * cs + qp * sn; k = k * cs + kp * sn; }
    else       { q = q * cs - qp * sn; k = k * cs - kp * sn; }
  }
  qh[((size_t)hh * 2048 + n) * 128 + d] = bf16_t(q * 0.08838834764831845f); // 1/sqrt(128)
  kh[((size_t)hh * 2048 + n) * 128 + d] = bf16_t(k);
  vT[((size_t)hh * 128 + d) * 2048 + n] = row[512 + d];
}

// ---------- causal flash attention, load-balanced pairs + swizzled dbuf LDS ----------
__global__ __launch_bounds__(256) void attn_kernel(const bf16_t* __restrict__ qh,
    const bf16_t* __restrict__ kh, const bf16_t* __restrict__ vT, bf16_t* __restrict__ av) {
  __shared__ alignas(16) char Kbuf[2][16384];    // [kv 64][d 128] bf16, chunk ^= row&15
  __shared__ alignas(16) char Vbuf[2][16384];    // [d 128][kv 64] bf16, chunk ^= row&7
  __shared__ alignas(16) bf16_t Ps[4][16 * 72];  // per-wave P, stride 72 (144B rows)
  const int p = blockIdx.x, h = blockIdx.y;
  const int tid = threadIdx.x, wid = tid >> 6, lane = tid & 63;
  const int lc = lane & 15, lg = lane >> 4;
  const int krow = wid * 4 + (lane >> 4);        // + i*16 ; stored chunk = lane&15
  const int vrow = wid * 8 + (lane >> 3);        // + i*32 ; stored chunk = lane&7

  auto stage = [&](int kv0, int d) {
#pragma unroll
    for (int i = 0; i < 4; ++i) {
      const int kr = i * 16 + krow;
      const int kch = (lane & 15) ^ (kr & 15);   // pre-swizzled global chunk
      gload_lds16(kh + ((size_t)h * 2048 + kv0 + kr) * 128 + kch * 8,
                  Kbuf[d] + i * 4096 + wid * 1024);
      const int vr = i * 32 + vrow;
      const int vch = (lane & 7) ^ (vr & 7);
      gload_lds16(vT + ((size_t)h * 128 + vr) * 2048 + kv0 + vch * 8,
                  Vbuf[d] + i * 4096 + wid * 1024);
    }
  };
#define FRK(d, row, ch) (*(const bfrag*)(Kbuf[d] + (row) * 256 + (((ch) ^ ((row) & 15)) << 4)))
#define FRV(d, row, ch) (*(const bfrag*)(Vbuf[d] + (row) * 128 + (((ch) ^ ((row) & 7)) << 4)))

#pragma unroll 1
  for (int half = 0; half < 2; ++half) {
    const int qt = half ? (31 - p) : p;
    const int nkv = qt + 1;
    const int qr = qt * 64 + wid * 16;
    const bf16_t* Qb = qh + ((size_t)h * 2048 + qr) * 128;
    bfrag qf[4];
#pragma unroll
    for (int ks = 0; ks < 4; ++ks)
      qf[ks] = *(const bfrag*)&Qb[lc * 128 + ks * 32 + lg * 8];
    f32x4 O[8] = {};
    float mr[4] = {-1e30f, -1e30f, -1e30f, -1e30f};
    float lsum[4] = {0.f, 0.f, 0.f, 0.f};

    stage(0, 0);
    asm volatile("s_waitcnt vmcnt(0)" ::: "memory");
    __builtin_amdgcn_s_barrier();

#pragma unroll 1
    for (int kt = 0; kt < nkv; ++kt) {
      const int d = kt & 1;
      const int kv0 = kt * 64;
      if (kt + 1 < nkv) stage(kv0 + 64, d ^ 1);  // overlap with compute
      f32x4 s[4];
#pragma unroll
      for (int c = 0; c < 4; ++c) {
        f32x4 a = {};
#pragma unroll
        for (int ks = 0; ks < 4; ++ks) {
          bfrag kf = FRK(d, c * 16 + lc, ks * 4 + lg);
          a = MFMA16(qf[ks], kf, a);
        }
        s[c] = a;
      }
      if (kt == qt) {  // diagonal tile: causal mask
#pragma unroll
        for (int c = 0; c < 4; ++c)
#pragma unroll
          for (int i = 0; i < 4; ++i)
            if (kv0 + c * 16 + lc > qr + lg * 4 + i) s[c][i] = -1e10f;
      }
      float pm[4];
#pragma unroll
      for (int i = 0; i < 4; ++i)
        pm[i] = fmaxf(fmaxf(s[0][i], s[1][i]), fmaxf(s[2][i], s[3][i]));
#pragma unroll
      for (int m = 1; m < 16; m <<= 1)
#pragma unroll
        for (int i = 0; i < 4; ++i) pm[i] = fmaxf(pm[i], __shfl_xor(pm[i], m));
      float al[4], rs[4];
#pragma unroll
      for (int i = 0; i < 4; ++i) {
        const float mn = fmaxf(mr[i], pm[i]);
        al[i] = __expf(mr[i] - mn);
        mr[i] = mn;
        rs[i] = 0.f;
      }
#pragma unroll
      for (int c = 0; c < 4; ++c)
#pragma unroll
        for (int i = 0; i < 4; ++i) {
          const float pv = __expf(s[c][i] - mr[i]);
          s[c][i] = pv; rs[i] += pv;
        }
#pragma unroll
      for (int m = 1; m < 16; m <<= 1)
#pragma unroll
        for (int i = 0; i < 4; ++i) rs[i] += __shfl_xor(rs[i], m);
#pragma unroll
      for (int i = 0; i < 4; ++i) lsum[i] = lsum[i] * al[i] + rs[i];
#pragma unroll
      for (int n = 0; n < 8; ++n)
#pragma unroll
        for (int i = 0; i < 4; ++i) O[n][i] *= al[i];
#pragma unroll
      for (int c = 0; c < 4; ++c)
#pragma unroll
        for (int i = 0; i < 4; ++i)
          Ps[wid][(lg * 4 + i) * 72 + c * 16 + lc] = bf16_t(s[c][i]);
#pragma unroll
      for (int k2 = 0; k2 < 2; ++k2) {
        bfrag pf = *(const bfrag*)((const char*)&Ps[wid][0] + lc * 144 + k2 * 64 + lg * 16);
#pragma unroll
        for (int n = 0; n < 8; ++n) {
          bfrag vf = FRV(d, n * 16 + lc, k2 * 4 + lg);
          O[n] = MFMA16(pf, vf, O[n]);
        }
      }
      if (kt + 1 < nkv) asm volatile("s_waitcnt vmcnt(0)" ::: "memory");  // next tile landed
      asm volatile("s_waitcnt lgkmcnt(0)" ::: "memory");
      __builtin_amdgcn_s_barrier();
    }
#pragma unroll
    for (int n = 0; n < 8; ++n)
#pragma unroll
      for (int i = 0; i < 4; ++i)
        av[(size_t)(qr + lg * 4 + i) * 2048 + h * 128 + n * 16 + lc] = bf16_t(O[n][i] / lsum[i]);
    __builtin_amdgcn_s_barrier();  // all waves done before next half re-stages buf0
  }
#undef FRK
#undef FRV
}

extern "C" void kernel_launch(void* const* d_in, const int* in_sizes, int n_in,
                              void* d_out, int out_size, void* d_ws, size_t ws_size,
                              hipStream_t stream) {
  const float* x        = (const float*)d_in[0];
  const float* ln_scale = (const float*)d_in[1];
  const float* ln_offset= (const float*)d_in[2];
  const float* w_qkv    = (const float*)d_in[3];   // [2048][6144]
  const float* w_ao     = (const float*)d_in[4];   // [2048][2048]
  const float* w_ff_in  = (const float*)d_in[5];   // [2048][8192]
  const float* b_ff_in  = (const float*)d_in[6];   // [8192]
  const float* w_ff_out = (const float*)d_in[7];   // [8192][2048]
  const float* b_ff_out = (const float*)d_in[8];   // [2048]
  float* out = (float*)d_out;

  char* ws = (char*)d_ws;
  bf16_t* wqkvT   = (bf16_t*)(ws);                  // [6144][2048]  (dead after qkv GEMM)
  bf16_t* waoT    = (bf16_t*)(ws + 25165824);       // [2048][2048]
  bf16_t* wffinT  = (bf16_t*)(ws + 33554432);       // [8192][2048]
  bf16_t* wffoutT = (bf16_t*)(ws + 67108864);       // [2048][8192]
  bf16_t* h       = (bf16_t*)(ws + 100663296);      // [2048][2048]
  bf16_t* qhb     = (bf16_t*)(ws + 109051904);      // [16][2048][128]
  bf16_t* khb     = (bf16_t*)(ws + 117440512);
  bf16_t* vTb     = (bf16_t*)(ws + 125829120);      // [16][128][2048]
  bf16_t* avb     = (bf16_t*)(ws + 134217728);      // [2048][2048]
  bf16_t* qkvb    = (bf16_t*)(ws + 142606336);      // [2048][6144]; later ff1 [2048][8192]
  bf16_t* ff1b    = qkvb;
  float*  pa      = (float*)(ws + 142606336);       // attn_out partials (over dead qkvb)
  float*  pf      = (float*)(ws);                   // ff_out partials (over dead weights)

  hipFuncSetAttribute((const void*)gemm8p<0>,  hipFuncAttributeMaxDynamicSharedMemorySize, 131072);
  hipFuncSetAttribute((const void*)gemm8p<8>,  hipFuncAttributeMaxDynamicSharedMemorySize, 131072);
  hipFuncSetAttribute((const void*)gemm8p<11>, hipFuncAttributeMaxDynamicSharedMemorySize, 131072);

  dim3 b256(256), b512(512);
  transpose_cvt<<<dim3(192, 64),  b256, 0, stream>>>(w_qkv,    wqkvT,   2048, 6144);
  transpose_cvt<<<dim3(64, 64),   b256, 0, stream>>>(w_ao,     waoT,    2048, 2048);
  transpose_cvt<<<dim3(256, 64),  b256, 0, stream>>>(w_ff_in,  wffinT,  2048, 8192);
  transpose_cvt<<<dim3(64, 256),  b256, 0, stream>>>(w_ff_out, wffoutT, 8192, 2048);
  ln_kernel<<<dim3(2048), b256, 0, stream>>>(x, ln_scale, ln_offset, h);

  gemm8p<8><<<dim3(24, 8, 1), b512, 131072, stream>>>(h, 2048, wqkvT, 2048,
      nullptr, nullptr, qkvb, 2048, 6144, 2048, 0);
  rope_kernel<<<dim3(2048, 16), dim3(128), 0, stream>>>(qkvb, qhb, khb, vTb);
  attn_kernel<<<dim3(16, 16), b256, 0, stream>>>(qhb, khb, vTb, avb);

  // attn_out: split-K=2 (K=1024 each)
  gemm8p<0><<<dim3(8, 8, 2), b512, 131072, stream>>>(avb, 2048, waoT, 2048,
      nullptr, pa, nullptr, 2048, 2048, 1024, (size_t)2048 * 2048);
  reduceP<2, false, false><<<dim3(4096), b256, 0, stream>>>(pa, pa + 4194304,
      nullptr, nullptr, nullptr, out, 4194304, 2047);

  gemm8p<11><<<dim3(32, 8, 1), b512, 131072, stream>>>(h, 2048, wffinT, 2048,
      b_ff_in, nullptr, ff1b, 2048, 8192, 2048, 0);

  // ff_out: split-K=4 (K=2048 each)
  gemm8p<0><<<dim3(8, 8, 4), b512, 131072, stream>>>(ff1b, 8192, wffoutT, 8192,
      nullptr, pf, nullptr, 2048, 2048, 2048, (size_t)2048 * 2048);
  reduceP<4, true, true><<<dim3(4096), b256, 0, stream>>>(pf, pf + 4194304,
      pf + 2 * 4194304, pf + 3 * 4194304, b_ff_out, out, 4194304, 2047);
}

// Round 6
// 437.272 us; speedup vs baseline: 1.0420x; 1.0341x over previous
//
#include <hip/hip_runtime.h>
#include <hip/hip_bf16.h>

using bf16_t = __hip_bfloat16;
typedef __attribute__((ext_vector_type(8))) __bf16 bfrag;   // 8 bf16 = 4 VGPR (MFMA A/B operand)
typedef __attribute__((ext_vector_type(4))) float f32x4;    // MFMA C/D operand

#define MFMA16(a, b, c) __builtin_amdgcn_mfma_f32_16x16x32_bf16((a), (b), (c), 0, 0, 0)

__device__ __forceinline__ void gload_lds16(const void* g, void* l) {
  // async global->LDS, 16B/lane; LDS dest = wave-uniform base + lane*16
  __builtin_amdgcn_global_load_lds((const __attribute__((address_space(1))) void*)g,
                                   (__attribute__((address_space(3))) void*)l, 16, 0, 0);
}

// ---------- weight transpose + f32->bf16 convert: in[K][N] f32 -> out[N][K] bf16 ----------
__global__ __launch_bounds__(256) void transpose_cvt(const float* __restrict__ in,
    bf16_t* __restrict__ out, int K, int N) {
  __shared__ float t[32][33];
  const int n0 = blockIdx.x * 32, k0 = blockIdx.y * 32;
  const int tx = threadIdx.x & 31, ty = threadIdx.x >> 5;   // 32 x 8
#pragma unroll
  for (int i = 0; i < 4; ++i)
    t[ty + i * 8][tx] = in[(size_t)(k0 + ty + i * 8) * N + n0 + tx];
  __syncthreads();
#pragma unroll
  for (int i = 0; i < 4; ++i)
    out[(size_t)(n0 + ty + i * 8) * K + k0 + tx] = bf16_t(t[tx][ty + i * 8]);
}

// ---------- LayerNorm: x f32 [2048][2048] -> h bf16 ----------
__global__ __launch_bounds__(256) void ln_kernel(const float* __restrict__ x,
    const float* __restrict__ sc, const float* __restrict__ of, bf16_t* __restrict__ h) {
  __shared__ float red[8];
  const int n = blockIdx.x, tid = threadIdx.x;
  const float* xr = x + (size_t)n * 2048;
  float4 a = ((const float4*)xr)[tid * 2];
  float4 b = ((const float4*)xr)[tid * 2 + 1];
  float s = a.x + a.y + a.z + a.w + b.x + b.y + b.z + b.w;
  float q = a.x * a.x + a.y * a.y + a.z * a.z + a.w * a.w +
            b.x * b.x + b.y * b.y + b.z * b.z + b.w * b.w;
#pragma unroll
  for (int m = 32; m; m >>= 1) { s += __shfl_xor(s, m); q += __shfl_xor(q, m); }
  if ((tid & 63) == 0) { red[(tid >> 6) * 2] = s; red[(tid >> 6) * 2 + 1] = q; }
  __syncthreads();
  s = red[0] + red[2] + red[4] + red[6];
  q = red[1] + red[3] + red[5] + red[7];
  const float mu = s * (1.f / 2048.f);
  const float inv = rsqrtf(q * (1.f / 2048.f) - mu * mu + 1e-5f);
  const int base = tid * 8;
  float v[8] = {a.x, a.y, a.z, a.w, b.x, b.y, b.z, b.w};
  bf16_t* hr = h + (size_t)n * 2048 + base;
#pragma unroll
  for (int j = 0; j < 8; ++j) hr[j] = bf16_t((v[j] - mu) * inv * sc[base + j] + of[base + j]);
}

// ---------- 8-phase 256x256 GEMM (round-3 schedule) + LDS-staged vector epilogue ----------
// EPI bits: 1=+bias[col], 2=gelu(tanh), 8=store bf16 to Cb (else f32 to Cf)
template <int EPI>
__global__ __launch_bounds__(512, 2) void gemm8p(
    const bf16_t* __restrict__ A, int lda, const bf16_t* __restrict__ BT, int ldb,
    const float* __restrict__ bias, float* __restrict__ Cf, bf16_t* __restrict__ Cb,
    int M, int N, int K, size_t splitStride) {
  extern __shared__ __align__(16) char lds[];   // 128 KiB: A slots [0,64K), B slots [64K,128K)
  const int tid = threadIdx.x, wid = tid >> 6, lane = tid & 63;
  const int lc = lane & 15, lg = lane >> 4;
  const int bm = blockIdx.y * 256, bn = blockIdx.x * 256;
  const int wr = wid >> 2, wc = wid & 3;              // 2 (M) x 4 (N) waves, each 128x64 out
  const int NT = K >> 6;                              // K-tiles of 64
  const int sr = wid * 16 + (lane >> 2);              // staging row (j=0); j=1 -> +128
  const int lgp = (lane & 3) ^ ((sr >> 1) & 3);       // pre-swizzled global k-chunk
  const size_t rA = (size_t)128 * lda, rB = (size_t)128 * ldb;
  const bf16_t* pA0 = A + (size_t)blockIdx.z * K + (size_t)(bm + sr) * lda + lgp * 8;
  const bf16_t* pA1 = pA0 + 32;
  const bf16_t* pB0 = BT + (size_t)blockIdx.z * K + (size_t)(bn + sr) * ldb + lgp * 8;
  const bf16_t* pB1 = pB0 + 32;
  auto stA0 = [&](int ts) { char* b = lds + (((ts & 1) * 2 + 0) << 14) + wid * 1024;
    gload_lds16(pA0, b); gload_lds16(pA0 + rA, b + 8192); pA0 += 64; };
  auto stA1 = [&](int ts) { char* b = lds + (((ts & 1) * 2 + 1) << 14) + wid * 1024;
    gload_lds16(pA1, b); gload_lds16(pA1 + rA, b + 8192); pA1 += 64; };
  auto stB0 = [&](int ts) { char* b = lds + 65536 + (((ts & 1) * 2 + 0) << 14) + wid * 1024;
    gload_lds16(pB0, b); gload_lds16(pB0 + rB, b + 8192); pB0 += 64; };
  auto stB1 = [&](int ts) { char* b = lds + 65536 + (((ts & 1) * 2 + 1) << 14) + wid * 1024;
    gload_lds16(pB1, b); gload_lds16(pB1 + rB, b + 8192); pB1 += 64; };

  // prologue: tile0 {A-k0,B-k0,A-k1,B-k1}, tile1 {A-k0,B-k0,A-k1}
  stA0(0); stB0(0); stA1(0); stB1(0); stA0(1); stB0(1); stA1(1);
  asm volatile("s_waitcnt vmcnt(6)" ::: "memory");    // tile0's 4 halves landed
  __builtin_amdgcn_s_barrier();

  f32x4 acc[8][4] = {};
#define FR(off, row) \
  (*(const bfrag*)(lds + (off) + (row) * 64 + ((lg ^ (((row) >> 1) & 3)) << 4)))

  for (int t = 0; t < NT; ++t) {
    const int d = t & 1;
    const int aoff0 = (d * 2 + 0) << 14, aoff1 = (d * 2 + 1) << 14;
    const int boff0 = 65536 + aoff0, boff1 = 65536 + aoff1;
    bfrag a[8];
    {
#pragma unroll
      for (int m = 0; m < 8; ++m) a[m] = FR(aoff0, wr * 128 + m * 16 + lc);
      bfrag b0 = FR(boff0, wc * 64 + lc);
      bfrag b1 = FR(boff0, wc * 64 + 16 + lc);
      if (t + 1 < NT) stB1(t + 1);
      __builtin_amdgcn_s_barrier();
      asm volatile("s_waitcnt lgkmcnt(0)" ::: "memory");
      __builtin_amdgcn_sched_barrier(0);
      __builtin_amdgcn_s_setprio(1);
#pragma unroll
      for (int m = 0; m < 8; ++m) {
        acc[m][0] = MFMA16(a[m], b0, acc[m][0]);
        acc[m][1] = MFMA16(a[m], b1, acc[m][1]);
      }
      __builtin_amdgcn_s_setprio(0);
      __builtin_amdgcn_s_barrier();
    }
    {
      bfrag b2 = FR(boff0, wc * 64 + 32 + lc);
      bfrag b3 = FR(boff0, wc * 64 + 48 + lc);
      if (t + 2 < NT) stA0(t + 2);
      __builtin_amdgcn_s_barrier();
      asm volatile("s_waitcnt lgkmcnt(0)" ::: "memory");
      __builtin_amdgcn_sched_barrier(0);
      __builtin_amdgcn_s_setprio(1);
#pragma unroll
      for (int m = 0; m < 8; ++m) {
        acc[m][2] = MFMA16(a[m], b2, acc[m][2]);
        acc[m][3] = MFMA16(a[m], b3, acc[m][3]);
      }
      __builtin_amdgcn_s_setprio(0);
      __builtin_amdgcn_s_barrier();
    }
    {
#pragma unroll
      for (int m = 0; m < 8; ++m) a[m] = FR(aoff1, wr * 128 + m * 16 + lc);
      bfrag b0 = FR(boff1, wc * 64 + lc);
      bfrag b1 = FR(boff1, wc * 64 + 16 + lc);
      if (t + 2 < NT) stB0(t + 2);
      __builtin_amdgcn_s_barrier();
      asm volatile("s_waitcnt lgkmcnt(0)" ::: "memory");
      __builtin_amdgcn_sched_barrier(0);
      __builtin_amdgcn_s_setprio(1);
#pragma unroll
      for (int m = 0; m < 8; ++m) {
        acc[m][0] = MFMA16(a[m], b0, acc[m][0]);
        acc[m][1] = MFMA16(a[m], b1, acc[m][1]);
      }
      __builtin_amdgcn_s_setprio(0);
      __builtin_amdgcn_s_barrier();
    }
    {
      bfrag b2 = FR(boff1, wc * 64 + 32 + lc);
      bfrag b3 = FR(boff1, wc * 64 + 48 + lc);
      if (t + 2 < NT) stA1(t + 2);
      __builtin_amdgcn_s_barrier();
      asm volatile("s_waitcnt lgkmcnt(0)" ::: "memory");
      __builtin_amdgcn_sched_barrier(0);
      __builtin_amdgcn_s_setprio(1);
#pragma unroll
      for (int m = 0; m < 8; ++m) {
        acc[m][2] = MFMA16(a[m], b2, acc[m][2]);
        acc[m][3] = MFMA16(a[m], b3, acc[m][3]);
      }
      __builtin_amdgcn_s_setprio(0);
      if (t < NT - 2) asm volatile("s_waitcnt vmcnt(6)" ::: "memory");
      else            asm volatile("s_waitcnt vmcnt(0)" ::: "memory");
      __builtin_amdgcn_s_barrier();
    }
  }
#undef FR
  // ---- epilogue: per-wave LDS transpose staging -> coalesced vector stores
  char* W = lds + wid * 16384;
  if (EPI & 8) {
    bf16_t* Wb = (bf16_t*)W;
#pragma unroll
    for (int mc = 0; mc < 2; ++mc) {
#pragma unroll
      for (int m4 = 0; m4 < 4; ++m4) {
#pragma unroll
        for (int n = 0; n < 4; ++n) {
          const int col = bn + wc * 64 + n * 16 + lc;
          float bv = (EPI & 1) ? bias[col] : 0.f;
#pragma unroll
          for (int i = 0; i < 4; ++i) {
            float v = acc[mc * 4 + m4][n][i];
            if (EPI & 1) v += bv;
            if (EPI & 2) v = 0.5f * v * (1.f + tanhf(0.7978845608028654f * (v + 0.044715f * v * v * v)));
            Wb[(m4 * 16 + lg * 4 + i) * 72 + n * 16 + lc] = bf16_t(v);
          }
        }
      }
      asm volatile("s_waitcnt lgkmcnt(0)" ::: "memory");
      __builtin_amdgcn_sched_barrier(0);
#pragma unroll
      for (int p = 0; p < 8; ++p) {
        const int rl = p * 8 + (lane >> 3), j = lane & 7;
        uint4 v = *(const uint4*)&Wb[rl * 72 + j * 8];
        const int grow = bm + wr * 128 + mc * 64 + rl;
        const int gcol = bn + wc * 64 + j * 8;
        *(uint4*)&Cb[(size_t)grow * N + gcol] = v;
      }
      asm volatile("s_waitcnt lgkmcnt(0)" ::: "memory");
      __builtin_amdgcn_sched_barrier(0);
    }
  } else {
    float* Wf = (float*)W;
    float* Cfz = Cf + (size_t)blockIdx.z * splitStride;
#pragma unroll
    for (int mc = 0; mc < 4; ++mc) {
#pragma unroll
      for (int m2 = 0; m2 < 2; ++m2) {
#pragma unroll
        for (int n = 0; n < 4; ++n) {
          const int col = bn + wc * 64 + n * 16 + lc;
          float bv = (EPI & 1) ? bias[col] : 0.f;
#pragma unroll
          for (int i = 0; i < 4; ++i) {
            float v = acc[mc * 2 + m2][n][i];
            if (EPI & 1) v += bv;
            if (EPI & 2) v = 0.5f * v * (1.f + tanhf(0.7978845608028654f * (v + 0.044715f * v * v * v)));
            Wf[(m2 * 16 + lg * 4 + i) * 72 + n * 16 + lc] = v;
          }
        }
      }
      asm volatile("s_waitcnt lgkmcnt(0)" ::: "memory");
      __builtin_amdgcn_sched_barrier(0);
#pragma unroll
      for (int p = 0; p < 8; ++p) {
        const int rl = p * 4 + (lane >> 4), j = lane & 15;
        float4 v = *(const float4*)&Wf[rl * 72 + j * 4];
        const int grow = bm + wr * 128 + mc * 32 + rl;
        const int gcol = bn + wc * 64 + j * 4;
        *(float4*)&Cfz[(size_t)grow * N + gcol] = v;
      }
      asm volatile("s_waitcnt lgkmcnt(0)" ::: "memory");
      __builtin_amdgcn_sched_barrier(0);
    }
  }
}

// ---------- split-K partial reduction ----------
template <int NP, bool ADDIN, bool BIAS>
__global__ __launch_bounds__(256) void reduceP(const float* __restrict__ p0,
    const float* __restrict__ p1, const float* __restrict__ p2,
    const float* __restrict__ p3, const float* __restrict__ bias,
    float* __restrict__ out, int total, int colmask) {
  const int i = (blockIdx.x * 256 + threadIdx.x) * 4;
  if (i >= total) return;
  float4 v = *(const float4*)(p0 + i);
  float4 w = *(const float4*)(p1 + i);
  v.x += w.x; v.y += w.y; v.z += w.z; v.w += w.w;
  if (NP == 4) {
    float4 u = *(const float4*)(p2 + i);
    float4 z = *(const float4*)(p3 + i);
    v.x += u.x + z.x; v.y += u.y + z.y; v.z += u.z + z.z; v.w += u.w + z.w;
  }
  if (BIAS) {
    float4 b = *(const float4*)(bias + (i & colmask));
    v.x += b.x; v.y += b.y; v.z += b.z; v.w += b.w;
  }
  if (ADDIN) {
    float4 o = *(const float4*)(out + i);
    v.x += o.x; v.y += o.y; v.z += o.z; v.w += o.w;
  }
  *(float4*)(out + i) = v;
}

// ---------- RoPE + head split ----------
__global__ __launch_bounds__(128) void rope_kernel(const bf16_t* __restrict__ qkv,
    bf16_t* __restrict__ qh, bf16_t* __restrict__ kh, bf16_t* __restrict__ vT) {
  const int n = blockIdx.x, hh = blockIdx.y;
  const int d = threadIdx.x;
  const int mp = hh >> 2, hi = hh & 3;
  const bf16_t* row = qkv + (size_t)n * 6144 + mp * 1536 + hi * 128;  // [q|v|k] each 512 per mp
  float q = __bfloat162float(row[d]);
  float k = __bfloat162float(row[1024 + d]);
  if (d < 64) {  // wave-uniform branch
    const float ang = (float)n * powf(10000.f, -(float)(d & ~1) / 64.f);
    const float sn = sinf(ang), cs = cosf(ang);
    const float qp = __shfl_xor(q, 1), kp = __shfl_xor(k, 1);
    if (d & 1) { q = q * cs + qp * sn; k = k * cs + kp * sn; }
    else       { q = q * cs - qp * sn; k = k * cs - kp * sn; }
  }
  qh[((size_t)hh * 2048 + n) * 128 + d] = bf16_t(q * 0.08838834764831845f); // 1/sqrt(128)
  kh[((size_t)hh * 2048 + n) * 128 + d] = bf16_t(k);
  vT[((size_t)hh * 128 + d) * 2048 + n] = row[512 + d];
}

// ---------- causal flash attention, pairs + KV-split(z=3), partial (O,m,l) output ----------
// block = (pair p, head h, z); q-tiles {p, 31-p}; per q-tile kv range [z*nkv/3,(z+1)*nkv/3).
__global__ __launch_bounds__(256) void attn_kernel(const bf16_t* __restrict__ qh,
    const bf16_t* __restrict__ kh, const bf16_t* __restrict__ vT,
    bf16_t* __restrict__ Op, float2* __restrict__ ml) {
  __shared__ alignas(16) char Kbuf[2][16384];    // [kv 64][d 128] bf16, chunk ^= row&15
  __shared__ alignas(16) char Vbuf[2][16384];    // [d 128][kv 64] bf16, chunk ^= row&7
  __shared__ alignas(16) bf16_t Ps[4][16 * 72];  // per-wave P, stride 72 (144B rows)
  const int p = blockIdx.x, h = blockIdx.y, z = blockIdx.z;
  const int tid = threadIdx.x, wid = tid >> 6, lane = tid & 63;
  const int lc = lane & 15, lg = lane >> 4;
  const int krow = wid * 4 + (lane >> 4);
  const int vrow = wid * 8 + (lane >> 3);

  auto stage = [&](int kv0, int d) {
#pragma unroll
    for (int i = 0; i < 4; ++i) {
      const int kr = i * 16 + krow;
      const int kch = (lane & 15) ^ (kr & 15);
      gload_lds16(kh + ((size_t)h * 2048 + kv0 + kr) * 128 + kch * 8,
                  Kbuf[d] + i * 4096 + wid * 1024);
      const int vr = i * 32 + vrow;
      const int vch = (lane & 7) ^ (vr & 7);
      gload_lds16(vT + ((size_t)h * 128 + vr) * 2048 + kv0 + vch * 8,
                  Vbuf[d] + i * 4096 + wid * 1024);
    }
  };
#define FRK(d, row, ch) (*(const bfrag*)(Kbuf[d] + (row) * 256 + (((ch) ^ ((row) & 15)) << 4)))
#define FRV(d, row, ch) (*(const bfrag*)(Vbuf[d] + (row) * 128 + (((ch) ^ ((row) & 7)) << 4)))

#pragma unroll 1
  for (int half = 0; half < 2; ++half) {
    const int qt = half ? (31 - p) : p;
    const int nkv = qt + 1;
    const int lo = (z * nkv) / 3, hi = ((z + 1) * nkv) / 3;
    const int nj = hi - lo;
    const int qr = qt * 64 + wid * 16;
    const bf16_t* Qb = qh + ((size_t)h * 2048 + qr) * 128;
    bfrag qf[4];
#pragma unroll
    for (int ks = 0; ks < 4; ++ks)
      qf[ks] = *(const bfrag*)&Qb[lc * 128 + ks * 32 + lg * 8];
    f32x4 O[8] = {};
    float mr[4] = {-1e30f, -1e30f, -1e30f, -1e30f};
    float lsum[4] = {0.f, 0.f, 0.f, 0.f};

    if (nj > 0) {
      stage(lo * 64, 0);
      asm volatile("s_waitcnt vmcnt(0)" ::: "memory");
      __builtin_amdgcn_s_barrier();
    }
#pragma unroll 1
    for (int j = 0; j < nj; ++j) {
      const int kt = lo + j, d = j & 1;
      const int kv0 = kt * 64;
      if (j + 1 < nj) stage(kv0 + 64, d ^ 1);  // overlap with compute
      f32x4 s[4];
#pragma unroll
      for (int c = 0; c < 4; ++c) {
        f32x4 a = {};
#pragma unroll
        for (int ks = 0; ks < 4; ++ks) {
          bfrag kf = FRK(d, c * 16 + lc, ks * 4 + lg);
          a = MFMA16(qf[ks], kf, a);
        }
        s[c] = a;
      }
      if (kt == qt) {  // diagonal tile: causal mask
#pragma unroll
        for (int c = 0; c < 4; ++c)
#pragma unroll
          for (int i = 0; i < 4; ++i)
            if (kv0 + c * 16 + lc > qr + lg * 4 + i) s[c][i] = -1e10f;
      }
      float pm[4];
#pragma unroll
      for (int i = 0; i < 4; ++i)
        pm[i] = fmaxf(fmaxf(s[0][i], s[1][i]), fmaxf(s[2][i], s[3][i]));
#pragma unroll
      for (int m = 1; m < 16; m <<= 1)
#pragma unroll
        for (int i = 0; i < 4; ++i) pm[i] = fmaxf(pm[i], __shfl_xor(pm[i], m));
      float al[4], rs[4];
#pragma unroll
      for (int i = 0; i < 4; ++i) {
        const float mn = fmaxf(mr[i], pm[i]);
        al[i] = __expf(mr[i] - mn);
        mr[i] = mn;
        rs[i] = 0.f;
      }
#pragma unroll
      for (int c = 0; c < 4; ++c)
#pragma unroll
        for (int i = 0; i < 4; ++i) {
          const float pv = __expf(s[c][i] - mr[i]);
          s[c][i] = pv; rs[i] += pv;
        }
#pragma unroll
      for (int m = 1; m < 16; m <<= 1)
#pragma unroll
        for (int i = 0; i < 4; ++i) rs[i] += __shfl_xor(rs[i], m);
#pragma unroll
      for (int i = 0; i < 4; ++i) lsum[i] = lsum[i] * al[i] + rs[i];
#pragma unroll
      for (int n = 0; n < 8; ++n)
#pragma unroll
        for (int i = 0; i < 4; ++i) O[n][i] *= al[i];
#pragma unroll
      for (int c = 0; c < 4; ++c)
#pragma unroll
        for (int i = 0; i < 4; ++i)
          Ps[wid][(lg * 4 + i) * 72 + c * 16 + lc] = bf16_t(s[c][i]);
#pragma unroll
      for (int k2 = 0; k2 < 2; ++k2) {
        bfrag pf = *(const bfrag*)((const char*)&Ps[wid][0] + lc * 144 + k2 * 64 + lg * 16);
#pragma unroll
        for (int n = 0; n < 8; ++n) {
          bfrag vf = FRV(d, n * 16 + lc, k2 * 4 + lg);
          O[n] = MFMA16(pf, vf, O[n]);
        }
      }
      if (j + 1 < nj) asm volatile("s_waitcnt vmcnt(0)" ::: "memory");
      asm volatile("s_waitcnt lgkmcnt(0)" ::: "memory");
      __builtin_amdgcn_s_barrier();
    }
    // write unnormalized partials (bf16) + per-row (m, l)
    const size_t rb = (size_t)(z * 16 + h) * 2048 + qr;
#pragma unroll
    for (int n = 0; n < 8; ++n)
#pragma unroll
      for (int i = 0; i < 4; ++i)
        Op[(rb + lg * 4 + i) * 128 + n * 16 + lc] = bf16_t(O[n][i]);
    if (lc == 0) {
#pragma unroll
      for (int i = 0; i < 4; ++i)
        ml[rb + lg * 4 + i] = make_float2(mr[i], lsum[i]);
    }
    __builtin_amdgcn_s_barrier();  // all waves done before next half re-stages buf0
  }
#undef FRK
#undef FRV
}

// ---------- combine z=3 attention partials -> av bf16 [2048][2048] ----------
__global__ __launch_bounds__(256) void attn_combine(const bf16_t* __restrict__ Op,
    const float2* __restrict__ ml, bf16_t* __restrict__ av) {
  const int idx = blockIdx.x * 256 + threadIdx.x;   // 16h * 2048r * 16 col-groups
  const int t = idx & 15, hr = idx >> 4;
  const int ZS = 16 * 2048;
  const size_t ZO = (size_t)ZS * 128;
  const float2 m0 = ml[hr], m1 = ml[ZS + hr], m2 = ml[2 * ZS + hr];
  const float M = fmaxf(fmaxf(m0.x, m1.x), m2.x);
  const float w0 = __expf(m0.x - M), w1 = __expf(m1.x - M), w2 = __expf(m2.x - M);
  const float inv = 1.f / (w0 * m0.y + w1 * m1.y + w2 * m2.y);
  const bf16_t* p0 = Op + (size_t)hr * 128 + t * 8;
  uint4 a0 = *(const uint4*)p0;
  uint4 a1 = *(const uint4*)(p0 + ZO);
  uint4 a2 = *(const uint4*)(p0 + 2 * ZO);
  const unsigned* u0 = (const unsigned*)&a0;
  const unsigned* u1 = (const unsigned*)&a1;
  const unsigned* u2 = (const unsigned*)&a2;
  bf16_t ov[8];
#pragma unroll
  for (int j = 0; j < 8; ++j) {
    const int w = j >> 1, sh = (j & 1) * 16;
    const float f0 = __uint_as_float(((u0[w] >> sh) & 0xffffu) << 16);
    const float f1 = __uint_as_float(((u1[w] >> sh) & 0xffffu) << 16);
    const float f2 = __uint_as_float(((u2[w] >> sh) & 0xffffu) << 16);
    ov[j] = bf16_t((w0 * f0 + w1 * f1 + w2 * f2) * inv);
  }
  const int row = hr & 2047, hh = hr >> 11;
  *(uint4*)(av + (size_t)row * 2048 + hh * 128 + t * 8) = *(const uint4*)ov;
}

extern "C" void kernel_launch(void* const* d_in, const int* in_sizes, int n_in,
                              void* d_out, int out_size, void* d_ws, size_t ws_size,
                              hipStream_t stream) {
  const float* x        = (const float*)d_in[0];
  const float* ln_scale = (const float*)d_in[1];
  const float* ln_offset= (const float*)d_in[2];
  const float* w_qkv    = (const float*)d_in[3];   // [2048][6144]
  const float* w_ao     = (const float*)d_in[4];   // [2048][2048]
  const float* w_ff_in  = (const float*)d_in[5];   // [2048][8192]
  const float* b_ff_in  = (const float*)d_in[6];   // [8192]
  const float* w_ff_out = (const float*)d_in[7];   // [8192][2048]
  const float* b_ff_out = (const float*)d_in[8];   // [2048]
  float* out = (float*)d_out;

  char* ws = (char*)d_ws;
  bf16_t* wqkvT   = (bf16_t*)(ws);                  // [6144][2048]; dead after qkv GEMM
  bf16_t* waoT    = (bf16_t*)(ws + 25165824);       // [2048][2048]
  bf16_t* wffinT  = (bf16_t*)(ws + 33554432);       // [8192][2048]
  bf16_t* wffoutT = (bf16_t*)(ws + 67108864);       // [2048][8192]
  bf16_t* h       = (bf16_t*)(ws + 100663296);      // [2048][2048]
  bf16_t* qhb     = (bf16_t*)(ws + 109051904);      // [16][2048][128]
  bf16_t* khb     = (bf16_t*)(ws + 117440512);
  bf16_t* vTb     = (bf16_t*)(ws + 125829120);      // [16][128][2048]
  bf16_t* avb     = (bf16_t*)(ws + 134217728);      // [2048][2048]
  bf16_t* qkvb    = (bf16_t*)(ws + 142606336);      // [2048][6144]; later ff1 [2048][8192]
  bf16_t* ff1b    = qkvb;
  float*  pa      = (float*)(ws + 142606336);       // attn_out partials (over dead qkv/ff1 region)
  float*  pf      = (float*)(ws);                   // ff_out partials (over dead weights)
  bf16_t* Opart   = (bf16_t*)(ws);                  // attn partials 3x[16][2048][128] bf16 (over dead wqkvT)
  float2* mlpart  = (float2*)(ws + 142606336 + 25165824);  // 3x[16][2048] float2 (past qkv data, dead)

  hipFuncSetAttribute((const void*)gemm8p<0>,  hipFuncAttributeMaxDynamicSharedMemorySize, 131072);
  hipFuncSetAttribute((const void*)gemm8p<8>,  hipFuncAttributeMaxDynamicSharedMemorySize, 131072);
  hipFuncSetAttribute((const void*)gemm8p<11>, hipFuncAttributeMaxDynamicSharedMemorySize, 131072);

  dim3 b256(256), b512(512);
  transpose_cvt<<<dim3(192, 64),  b256, 0, stream>>>(w_qkv,    wqkvT,   2048, 6144);
  transpose_cvt<<<dim3(64, 64),   b256, 0, stream>>>(w_ao,     waoT,    2048, 2048);
  transpose_cvt<<<dim3(256, 64),  b256, 0, stream>>>(w_ff_in,  wffinT,  2048, 8192);
  transpose_cvt<<<dim3(64, 256),  b256, 0, stream>>>(w_ff_out, wffoutT, 8192, 2048);
  ln_kernel<<<dim3(2048), b256, 0, stream>>>(x, ln_scale, ln_offset, h);

  gemm8p<8><<<dim3(24, 8, 1), b512, 131072, stream>>>(h, 2048, wqkvT, 2048,
      nullptr, nullptr, qkvb, 2048, 6144, 2048, 0);
  rope_kernel<<<dim3(2048, 16), dim3(128), 0, stream>>>(qkvb, qhb, khb, vTb);

  // attention: 16 pairs x 16 heads x 3 KV-splits = 768 blocks (3/CU), then combine
  attn_kernel<<<dim3(16, 16, 3), b256, 0, stream>>>(qhb, khb, vTb, Opart, mlpart);
  attn_combine<<<dim3(2048), b256, 0, stream>>>(Opart, mlpart, avb);

  // attn_out: split-K=2 (K=1024 each)
  gemm8p<0><<<dim3(8, 8, 2), b512, 131072, stream>>>(avb, 2048, waoT, 2048,
      nullptr, pa, nullptr, 2048, 2048, 1024, (size_t)2048 * 2048);
  reduceP<2, false, false><<<dim3(4096), b256, 0, stream>>>(pa, pa + 4194304,
      nullptr, nullptr, nullptr, out, 4194304, 2047);

  gemm8p<11><<<dim3(32, 8, 1), b512, 131072, stream>>>(h, 2048, wffinT, 2048,
      b_ff_in, nullptr, ff1b, 2048, 8192, 2048, 0);

  // ff_out: split-K=4 (K=2048 each)
  gemm8p<0><<<dim3(8, 8, 4), b512, 131072, stream>>>(ff1b, 8192, wffoutT, 8192,
      nullptr, pf, nullptr, 2048, 2048, 2048, (size_t)2048 * 2048);
  reduceP<4, true, true><<<dim3(4096), b256, 0, stream>>>(pf, pf + 4194304,
      pf + 2 * 4194304, pf + 3 * 4194304, b_ff_out, out, 4194304, 2047);
}

// Round 7
// 421.839 us; speedup vs baseline: 1.0801x; 1.0366x over previous
//
#include <hip/hip_runtime.h>
#include <hip/hip_bf16.h>

using bf16_t = __hip_bfloat16;
typedef __attribute__((ext_vector_type(8))) __bf16 bfrag;   // 8 bf16 = 4 VGPR (MFMA A/B operand)
typedef __attribute__((ext_vector_type(4))) float f32x4;    // MFMA C/D operand

#define MFMA16(a, b, c) __builtin_amdgcn_mfma_f32_16x16x32_bf16((a), (b), (c), 0, 0, 0)

__device__ __forceinline__ void gload_lds16(const void* g, void* l) {
  // async global->LDS, 16B/lane; LDS dest = wave-uniform base + lane*16
  __builtin_amdgcn_global_load_lds((const __attribute__((address_space(1))) void*)g,
                                   (__attribute__((address_space(3))) void*)l, 16, 0, 0);
}

__device__ __forceinline__ float bf2f(unsigned u) { return __uint_as_float(u << 16); }

// ---------- weight transpose + f32->bf16 convert: in[K][N] f32 -> out[N][K] bf16 ----------
// 64x64 tiles: coalesced 256B row loads, 128B bf16 row writes.
__global__ __launch_bounds__(256) void transpose_cvt(const float* __restrict__ in,
    bf16_t* __restrict__ out, int K, int N) {
  __shared__ float t[64][65];
  const int n0 = blockIdx.x * 64, k0 = blockIdx.y * 64;
  const int tx = threadIdx.x & 15, ty = threadIdx.x >> 4;   // 16 x 16
#pragma unroll
  for (int i = 0; i < 4; ++i) {
    float4 v = *(const float4*)&in[(size_t)(k0 + i * 16 + ty) * N + n0 + tx * 4];
    t[i * 16 + ty][tx * 4 + 0] = v.x; t[i * 16 + ty][tx * 4 + 1] = v.y;
    t[i * 16 + ty][tx * 4 + 2] = v.z; t[i * 16 + ty][tx * 4 + 3] = v.w;
  }
  __syncthreads();
#pragma unroll
  for (int i = 0; i < 4; ++i) {
    const int n = i * 16 + ty;
    bf16_t w[4];
#pragma unroll
    for (int j = 0; j < 4; ++j) w[j] = bf16_t(t[tx * 4 + j][n]);
    *(uint2*)&out[(size_t)(n0 + n) * K + k0 + tx * 4] = *(const uint2*)w;
  }
}

// ---------- LayerNorm: x f32 [2048][2048] -> h bf16 ----------
__global__ __launch_bounds__(256) void ln_kernel(const float* __restrict__ x,
    const float* __restrict__ sc, const float* __restrict__ of, bf16_t* __restrict__ h) {
  __shared__ float red[8];
  const int n = blockIdx.x, tid = threadIdx.x;
  const float* xr = x + (size_t)n * 2048;
  float4 a = ((const float4*)xr)[tid * 2];
  float4 b = ((const float4*)xr)[tid * 2 + 1];
  float s = a.x + a.y + a.z + a.w + b.x + b.y + b.z + b.w;
  float q = a.x * a.x + a.y * a.y + a.z * a.z + a.w * a.w +
            b.x * b.x + b.y * b.y + b.z * b.z + b.w * b.w;
#pragma unroll
  for (int m = 32; m; m >>= 1) { s += __shfl_xor(s, m); q += __shfl_xor(q, m); }
  if ((tid & 63) == 0) { red[(tid >> 6) * 2] = s; red[(tid >> 6) * 2 + 1] = q; }
  __syncthreads();
  s = red[0] + red[2] + red[4] + red[6];
  q = red[1] + red[3] + red[5] + red[7];
  const float mu = s * (1.f / 2048.f);
  const float inv = rsqrtf(q * (1.f / 2048.f) - mu * mu + 1e-5f);
  const int base = tid * 8;
  float v[8] = {a.x, a.y, a.z, a.w, b.x, b.y, b.z, b.w};
  bf16_t* hr = h + (size_t)n * 2048 + base;
#pragma unroll
  for (int j = 0; j < 8; ++j) hr[j] = bf16_t((v[j] - mu) * inv * sc[base + j] + of[base + j]);
}

// ---------- 2-phase 256x256 GEMM: C = A[M][lda](bf16) * BT[N][ldb]^T ----------
// Per K-tile: 2 phases (kk0, kk1), 32 MFMA + 12 ds_read_b128 + 4 gload_lds each.
// Stage ledger: phase A stages A1,B1(t+1) [other-parity slots]; phase B stages
// A0,B0(t+2) [own-parity slots, reads finished in phase A]. vmcnt(8) = 2 phases
// x 4 loads in flight. EPI bits: 1=+bias, 2=gelu, 8=store bf16 (else f32)
template <int EPI>
__global__ __launch_bounds__(512, 2) void gemm2p(
    const bf16_t* __restrict__ A, int lda, const bf16_t* __restrict__ BT, int ldb,
    const float* __restrict__ bias, float* __restrict__ Cf, bf16_t* __restrict__ Cb,
    int M, int N, int K, size_t splitStride) {
  extern __shared__ __align__(16) char lds[];   // 128 KiB: A slots [0,64K), B slots [64K,128K)
  const int tid = threadIdx.x, wid = tid >> 6, lane = tid & 63;
  const int lc = lane & 15, lg = lane >> 4;
  const int bm = blockIdx.y * 256, bn = blockIdx.x * 256;
  const int wr = wid >> 2, wc = wid & 3;              // 2 (M) x 4 (N) waves, each 128x64 out
  const int NT = K >> 6;                              // K-tiles of 64
  const int sr = wid * 16 + (lane >> 2);              // staging row (j=0); j=1 -> +128
  const int lgp = (lane & 3) ^ ((sr >> 1) & 3);       // pre-swizzled global k-chunk
  const size_t rA = (size_t)128 * lda, rB = (size_t)128 * ldb;
  const bf16_t* pA0 = A + (size_t)blockIdx.z * K + (size_t)(bm + sr) * lda + lgp * 8;
  const bf16_t* pA1 = pA0 + 32;
  const bf16_t* pB0 = BT + (size_t)blockIdx.z * K + (size_t)(bn + sr) * ldb + lgp * 8;
  const bf16_t* pB1 = pB0 + 32;
  auto stA0 = [&](int ts) { char* b = lds + (((ts & 1) * 2 + 0) << 14) + wid * 1024;
    gload_lds16(pA0, b); gload_lds16(pA0 + rA, b + 8192); pA0 += 64; };
  auto stA1 = [&](int ts) { char* b = lds + (((ts & 1) * 2 + 1) << 14) + wid * 1024;
    gload_lds16(pA1, b); gload_lds16(pA1 + rA, b + 8192); pA1 += 64; };
  auto stB0 = [&](int ts) { char* b = lds + 65536 + (((ts & 1) * 2 + 0) << 14) + wid * 1024;
    gload_lds16(pB0, b); gload_lds16(pB0 + rB, b + 8192); pB0 += 64; };
  auto stB1 = [&](int ts) { char* b = lds + 65536 + (((ts & 1) * 2 + 1) << 14) + wid * 1024;
    gload_lds16(pB1, b); gload_lds16(pB1 + rB, b + 8192); pB1 += 64; };

  // prologue: tile0 all 4 halves + tile1 {A0,B0} = 12 loads
  stA0(0); stB0(0); stA1(0); stB1(0); stA0(1); stB0(1);
  asm volatile("s_waitcnt vmcnt(8)" ::: "memory");    // tile0 A0,B0 landed
  __builtin_amdgcn_s_barrier();

  f32x4 acc[8][4] = {};
#define FR(off, row) \
  (*(const bfrag*)(lds + (off) + (row) * 64 + ((lg ^ (((row) >> 1) & 3)) << 4)))

  for (int t = 0; t < NT; ++t) {
    const int d = t & 1;
    const int aoff0 = (d * 2 + 0) << 14, aoff1 = (d * 2 + 1) << 14;
    const int boff0 = 65536 + aoff0, boff1 = 65536 + aoff1;
    // ---- phase A: kk0, full 8m x 4n; stages A1,B1(t+1)
    {
      bfrag a[8], b[4];
#pragma unroll
      for (int m = 0; m < 8; ++m) a[m] = FR(aoff0, wr * 128 + m * 16 + lc);
#pragma unroll
      for (int n = 0; n < 4; ++n) b[n] = FR(boff0, wc * 64 + n * 16 + lc);
      if (t + 1 < NT) { stA1(t + 1); stB1(t + 1); }
      __builtin_amdgcn_s_barrier();
      asm volatile("s_waitcnt lgkmcnt(0)" ::: "memory");
      __builtin_amdgcn_sched_barrier(0);
      __builtin_amdgcn_s_setprio(1);
#pragma unroll
      for (int m = 0; m < 8; ++m)
#pragma unroll
        for (int n = 0; n < 4; ++n) acc[m][n] = MFMA16(a[m], b[n], acc[m][n]);
      __builtin_amdgcn_s_setprio(0);
      if (t < NT - 2) asm volatile("s_waitcnt vmcnt(8)" ::: "memory");
      else            asm volatile("s_waitcnt vmcnt(0)" ::: "memory");
      __builtin_amdgcn_s_barrier();
    }
    // ---- phase B: kk1, full 8m x 4n; stages A0,B0(t+2)
    {
      bfrag a[8], b[4];
#pragma unroll
      for (int m = 0; m < 8; ++m) a[m] = FR(aoff1, wr * 128 + m * 16 + lc);
#pragma unroll
      for (int n = 0; n < 4; ++n) b[n] = FR(boff1, wc * 64 + n * 16 + lc);
      if (t + 2 < NT) { stA0(t + 2); stB0(t + 2); }
      __builtin_amdgcn_s_barrier();
      asm volatile("s_waitcnt lgkmcnt(0)" ::: "memory");
      __builtin_amdgcn_sched_barrier(0);
      __builtin_amdgcn_s_setprio(1);
#pragma unroll
      for (int m = 0; m < 8; ++m)
#pragma unroll
        for (int n = 0; n < 4; ++n) acc[m][n] = MFMA16(a[m], b[n], acc[m][n]);
      __builtin_amdgcn_s_setprio(0);
      if (t < NT - 2) asm volatile("s_waitcnt vmcnt(8)" ::: "memory");
      else            asm volatile("s_waitcnt vmcnt(0)" ::: "memory");
      __builtin_amdgcn_s_barrier();
    }
  }
#undef FR
  // ---- epilogue: per-wave LDS staging -> coalesced vector stores
  char* W = lds + wid * 16384;
  if (EPI & 8) {
    bf16_t* Wb = (bf16_t*)W;
    bf16_t* Cbz = Cb + (size_t)blockIdx.z * splitStride;
#pragma unroll
    for (int mc = 0; mc < 2; ++mc) {
#pragma unroll
      for (int m4 = 0; m4 < 4; ++m4) {
#pragma unroll
        for (int n = 0; n < 4; ++n) {
          const int col = bn + wc * 64 + n * 16 + lc;
          float bv = (EPI & 1) ? bias[col] : 0.f;
#pragma unroll
          for (int i = 0; i < 4; ++i) {
            float v = acc[mc * 4 + m4][n][i];
            if (EPI & 1) v += bv;
            if (EPI & 2) v = 0.5f * v * (1.f + tanhf(0.7978845608028654f * (v + 0.044715f * v * v * v)));
            Wb[(m4 * 16 + lg * 4 + i) * 72 + n * 16 + lc] = bf16_t(v);
          }
        }
      }
      asm volatile("s_waitcnt lgkmcnt(0)" ::: "memory");
      __builtin_amdgcn_sched_barrier(0);
#pragma unroll
      for (int p = 0; p < 8; ++p) {
        const int rl = p * 8 + (lane >> 3), j = lane & 7;
        uint4 v = *(const uint4*)&Wb[rl * 72 + j * 8];
        const int grow = bm + wr * 128 + mc * 64 + rl;
        const int gcol = bn + wc * 64 + j * 8;
        *(uint4*)&Cbz[(size_t)grow * N + gcol] = v;
      }
      asm volatile("s_waitcnt lgkmcnt(0)" ::: "memory");
      __builtin_amdgcn_sched_barrier(0);
    }
  } else {
    float* Wf = (float*)W;
    float* Cfz = Cf + (size_t)blockIdx.z * splitStride;
#pragma unroll
    for (int mc = 0; mc < 4; ++mc) {
#pragma unroll
      for (int m2 = 0; m2 < 2; ++m2) {
#pragma unroll
        for (int n = 0; n < 4; ++n) {
          const int col = bn + wc * 64 + n * 16 + lc;
          float bv = (EPI & 1) ? bias[col] : 0.f;
#pragma unroll
          for (int i = 0; i < 4; ++i) {
            float v = acc[mc * 2 + m2][n][i];
            if (EPI & 1) v += bv;
            if (EPI & 2) v = 0.5f * v * (1.f + tanhf(0.7978845608028654f * (v + 0.044715f * v * v * v)));
            Wf[(m2 * 16 + lg * 4 + i) * 72 + n * 16 + lc] = v;
          }
        }
      }
      asm volatile("s_waitcnt lgkmcnt(0)" ::: "memory");
      __builtin_amdgcn_sched_barrier(0);
#pragma unroll
      for (int p = 0; p < 8; ++p) {
        const int rl = p * 4 + (lane >> 4), j = lane & 15;
        float4 v = *(const float4*)&Wf[rl * 72 + j * 4];
        const int grow = bm + wr * 128 + mc * 32 + rl;
        const int gcol = bn + wc * 64 + j * 4;
        *(float4*)&Cfz[(size_t)grow * N + gcol] = v;
      }
      asm volatile("s_waitcnt lgkmcnt(0)" ::: "memory");
      __builtin_amdgcn_sched_barrier(0);
    }
  }
}

// ---------- split-K f32 partial reduction ----------
template <int NP, bool ADDIN, bool BIAS>
__global__ __launch_bounds__(256) void reduceP(const float* __restrict__ p0,
    const float* __restrict__ p1, const float* __restrict__ p2,
    const float* __restrict__ p3, const float* __restrict__ bias,
    float* __restrict__ out, int total, int colmask) {
  const int i = (blockIdx.x * 256 + threadIdx.x) * 4;
  if (i >= total) return;
  float4 v = *(const float4*)(p0 + i);
  float4 w = *(const float4*)(p1 + i);
  v.x += w.x; v.y += w.y; v.z += w.z; v.w += w.w;
  if (NP == 4) {
    float4 u = *(const float4*)(p2 + i);
    float4 z = *(const float4*)(p3 + i);
    v.x += u.x + z.x; v.y += u.y + z.y; v.z += u.z + z.z; v.w += u.w + z.w;
  }
  if (BIAS) {
    float4 b = *(const float4*)(bias + (i & colmask));
    v.x += b.x; v.y += b.y; v.z += b.z; v.w += b.w;
  }
  if (ADDIN) {
    float4 o = *(const float4*)(out + i);
    v.x += o.x; v.y += o.y; v.z += o.z; v.w += o.w;
  }
  *(float4*)(out + i) = v;
}

// ---------- split-K bf16 partial reduction (4 parts) -> f32 out ----------
__global__ __launch_bounds__(256) void reduce4b(const bf16_t* __restrict__ p0,
    const bf16_t* __restrict__ p1, const bf16_t* __restrict__ p2,
    const bf16_t* __restrict__ p3, float* __restrict__ out, int total) {
  const int i = (blockIdx.x * 256 + threadIdx.x) * 8;
  if (i >= total) return;
  uint4 a0 = *(const uint4*)(p0 + i);
  uint4 a1 = *(const uint4*)(p1 + i);
  uint4 a2 = *(const uint4*)(p2 + i);
  uint4 a3 = *(const uint4*)(p3 + i);
  const unsigned* u0 = (const unsigned*)&a0;
  const unsigned* u1 = (const unsigned*)&a1;
  const unsigned* u2 = (const unsigned*)&a2;
  const unsigned* u3 = (const unsigned*)&a3;
  float r[8];
#pragma unroll
  for (int j = 0; j < 8; ++j) {
    const int w = j >> 1, sh = (j & 1) * 16;
    r[j] = bf2f((u0[w] >> sh) & 0xffffu) + bf2f((u1[w] >> sh) & 0xffffu) +
           bf2f((u2[w] >> sh) & 0xffffu) + bf2f((u3[w] >> sh) & 0xffffu);
  }
  *(float4*)(out + i) = make_float4(r[0], r[1], r[2], r[3]);
  *(float4*)(out + i + 4) = make_float4(r[4], r[5], r[6], r[7]);
}

// ---------- RoPE + head split ----------
__global__ __launch_bounds__(128) void rope_kernel(const bf16_t* __restrict__ qkv,
    bf16_t* __restrict__ qh, bf16_t* __restrict__ kh, bf16_t* __restrict__ vT) {
  const int n = blockIdx.x, hh = blockIdx.y;
  const int d = threadIdx.x;
  const int mp = hh >> 2, hi = hh & 3;
  const bf16_t* row = qkv + (size_t)n * 6144 + mp * 1536 + hi * 128;  // [q|v|k] each 512 per mp
  float q = __bfloat162float(row[d]);
  float k = __bfloat162float(row[1024 + d]);
  if (d < 64) {  // wave-uniform branch
    const float ang = (float)n * powf(10000.f, -(float)(d & ~1) / 64.f);
    const float sn = sinf(ang), cs = cosf(ang);
    const float qp = __shfl_xor(q, 1), kp = __shfl_xor(k, 1);
    if (d & 1) { q = q * cs + qp * sn; k = k * cs + kp * sn; }
    else       { q = q * cs - qp * sn; k = k * cs - kp * sn; }
  }
  qh[((size_t)hh * 2048 + n) * 128 + d] = bf16_t(q * 0.08838834764831845f); // 1/sqrt(128)
  kh[((size_t)hh * 2048 + n) * 128 + d] = bf16_t(k);
  vT[((size_t)hh * 128 + d) * 2048 + n] = row[512 + d];
}

// ---------- causal flash attention, pairs + KV-split(z=3), partial (O,m,l) output ----------
__global__ __launch_bounds__(256) void attn_kernel(const bf16_t* __restrict__ qh,
    const bf16_t* __restrict__ kh, const bf16_t* __restrict__ vT,
    bf16_t* __restrict__ Op, float2* __restrict__ ml) {
  __shared__ alignas(16) char Kbuf[2][16384];    // [kv 64][d 128] bf16, chunk ^= row&15
  __shared__ alignas(16) char Vbuf[2][16384];    // [d 128][kv 64] bf16, chunk ^= row&7
  __shared__ alignas(16) bf16_t Ps[4][16 * 72];  // per-wave P, stride 72
  const int p = blockIdx.x, h = blockIdx.y, z = blockIdx.z;
  const int tid = threadIdx.x, wid = tid >> 6, lane = tid & 63;
  const int lc = lane & 15, lg = lane >> 4;
  const int krow = wid * 4 + (lane >> 4);
  const int vrow = wid * 8 + (lane >> 3);

  auto stage = [&](int kv0, int d) {
#pragma unroll
    for (int i = 0; i < 4; ++i) {
      const int kr = i * 16 + krow;
      const int kch = (lane & 15) ^ (kr & 15);
      gload_lds16(kh + ((size_t)h * 2048 + kv0 + kr) * 128 + kch * 8,
                  Kbuf[d] + i * 4096 + wid * 1024);
      const int vr = i * 32 + vrow;
      const int vch = (lane & 7) ^ (vr & 7);
      gload_lds16(vT + ((size_t)h * 128 + vr) * 2048 + kv0 + vch * 8,
                  Vbuf[d] + i * 4096 + wid * 1024);
    }
  };
#define FRK(d, row, ch) (*(const bfrag*)(Kbuf[d] + (row) * 256 + (((ch) ^ ((row) & 15)) << 4)))
#define FRV(d, row, ch) (*(const bfrag*)(Vbuf[d] + (row) * 128 + (((ch) ^ ((row) & 7)) << 4)))

#pragma unroll 1
  for (int half = 0; half < 2; ++half) {
    const int qt = half ? (31 - p) : p;
    const int nkv = qt + 1;
    const int lo = (z * nkv) / 3, hi = ((z + 1) * nkv) / 3;
    const int nj = hi - lo;
    const int qr = qt * 64 + wid * 16;
    const bf16_t* Qb = qh + ((size_t)h * 2048 + qr) * 128;
    bfrag qf[4];
#pragma unroll
    for (int ks = 0; ks < 4; ++ks)
      qf[ks] = *(const bfrag*)&Qb[lc * 128 + ks * 32 + lg * 8];
    f32x4 O[8] = {};
    float mr[4] = {-1e30f, -1e30f, -1e30f, -1e30f};
    float lsum[4] = {0.f, 0.f, 0.f, 0.f};

    if (nj > 0) {
      stage(lo * 64, 0);
      asm volatile("s_waitcnt vmcnt(0)" ::: "memory");
      __builtin_amdgcn_s_barrier();
    }
#pragma unroll 1
    for (int j = 0; j < nj; ++j) {
      const int kt = lo + j, d = j & 1;
      const int kv0 = kt * 64;
      if (j + 1 < nj) stage(kv0 + 64, d ^ 1);  // overlap with compute
      f32x4 s[4];
#pragma unroll
      for (int c = 0; c < 4; ++c) {
        f32x4 a = {};
#pragma unroll
        for (int ks = 0; ks < 4; ++ks) {
          bfrag kf = FRK(d, c * 16 + lc, ks * 4 + lg);
          a = MFMA16(qf[ks], kf, a);
        }
        s[c] = a;
      }
      if (kt == qt) {  // diagonal tile: causal mask
#pragma unroll
        for (int c = 0; c < 4; ++c)
#pragma unroll
          for (int i = 0; i < 4; ++i)
            if (kv0 + c * 16 + lc > qr + lg * 4 + i) s[c][i] = -1e10f;
      }
      float pm[4];
#pragma unroll
      for (int i = 0; i < 4; ++i)
        pm[i] = fmaxf(fmaxf(s[0][i], s[1][i]), fmaxf(s[2][i], s[3][i]));
#pragma unroll
      for (int m = 1; m < 16; m <<= 1)
#pragma unroll
        for (int i = 0; i < 4; ++i) pm[i] = fmaxf(pm[i], __shfl_xor(pm[i], m));
      float al[4], rs[4];
#pragma unroll
      for (int i = 0; i < 4; ++i) {
        const float mn = fmaxf(mr[i], pm[i]);
        al[i] = __expf(mr[i] - mn);
        mr[i] = mn;
        rs[i] = 0.f;
      }
#pragma unroll
      for (int c = 0; c < 4; ++c)
#pragma unroll
        for (int i = 0; i < 4; ++i) {
          const float pv = __expf(s[c][i] - mr[i]);
          s[c][i] = pv; rs[i] += pv;
        }
#pragma unroll
      for (int m = 1; m < 16; m <<= 1)
#pragma unroll
        for (int i = 0; i < 4; ++i) rs[i] += __shfl_xor(rs[i], m);
#pragma unroll
      for (int i = 0; i < 4; ++i) lsum[i] = lsum[i] * al[i] + rs[i];
#pragma unroll
      for (int n = 0; n < 8; ++n)
#pragma unroll
        for (int i = 0; i < 4; ++i) O[n][i] *= al[i];
#pragma unroll
      for (int c = 0; c < 4; ++c)
#pragma unroll
        for (int i = 0; i < 4; ++i)
          Ps[wid][(lg * 4 + i) * 72 + c * 16 + lc] = bf16_t(s[c][i]);
#pragma unroll
      for (int k2 = 0; k2 < 2; ++k2) {
        bfrag pf = *(const bfrag*)((const char*)&Ps[wid][0] + lc * 144 + k2 * 64 + lg * 16);
#pragma unroll
        for (int n = 0; n < 8; ++n) {
          bfrag vf = FRV(d, n * 16 + lc, k2 * 4 + lg);
          O[n] = MFMA16(pf, vf, O[n]);
        }
      }
      if (j + 1 < nj) asm volatile("s_waitcnt vmcnt(0)" ::: "memory");
      asm volatile("s_waitcnt lgkmcnt(0)" ::: "memory");
      __builtin_amdgcn_s_barrier();
    }
    const size_t rb = (size_t)(z * 16 + h) * 2048 + qr;
#pragma unroll
    for (int n = 0; n < 8; ++n)
#pragma unroll
      for (int i = 0; i < 4; ++i)
        Op[(rb + lg * 4 + i) * 128 + n * 16 + lc] = bf16_t(O[n][i]);
    if (lc == 0) {
#pragma unroll
      for (int i = 0; i < 4; ++i)
        ml[rb + lg * 4 + i] = make_float2(mr[i], lsum[i]);
    }
    __builtin_amdgcn_s_barrier();
  }
#undef FRK
#undef FRV
}

// ---------- combine z=3 attention partials -> av bf16 [2048][2048] ----------
__global__ __launch_bounds__(256) void attn_combine(const bf16_t* __restrict__ Op,
    const float2* __restrict__ ml, bf16_t* __restrict__ av) {
  const int idx = blockIdx.x * 256 + threadIdx.x;
  const int t = idx & 15, hr = idx >> 4;
  const int ZS = 16 * 2048;
  const size_t ZO = (size_t)ZS * 128;
  const float2 m0 = ml[hr], m1 = ml[ZS + hr], m2 = ml[2 * ZS + hr];
  const float M = fmaxf(fmaxf(m0.x, m1.x), m2.x);
  const float w0 = __expf(m0.x - M), w1 = __expf(m1.x - M), w2 = __expf(m2.x - M);
  const float inv = 1.f / (w0 * m0.y + w1 * m1.y + w2 * m2.y);
  const bf16_t* p0 = Op + (size_t)hr * 128 + t * 8;
  uint4 a0 = *(const uint4*)p0;
  uint4 a1 = *(const uint4*)(p0 + ZO);
  uint4 a2 = *(const uint4*)(p0 + 2 * ZO);
  const unsigned* u0 = (const unsigned*)&a0;
  const unsigned* u1 = (const unsigned*)&a1;
  const unsigned* u2 = (const unsigned*)&a2;
  bf16_t ov[8];
#pragma unroll
  for (int j = 0; j < 8; ++j) {
    const int w = j >> 1, sh = (j & 1) * 16;
    ov[j] = bf16_t((w0 * bf2f((u0[w] >> sh) & 0xffffu) +
                    w1 * bf2f((u1[w] >> sh) & 0xffffu) +
                    w2 * bf2f((u2[w] >> sh) & 0xffffu)) * inv);
  }
  const int row = hr & 2047, hh = hr >> 11;
  *(uint4*)(av + (size_t)row * 2048 + hh * 128 + t * 8) = *(const uint4*)ov;
}

extern "C" void kernel_launch(void* const* d_in, const int* in_sizes, int n_in,
                              void* d_out, int out_size, void* d_ws, size_t ws_size,
                              hipStream_t stream) {
  const float* x        = (const float*)d_in[0];
  const float* ln_scale = (const float*)d_in[1];
  const float* ln_offset= (const float*)d_in[2];
  const float* w_qkv    = (const float*)d_in[3];   // [2048][6144]
  const float* w_ao     = (const float*)d_in[4];   // [2048][2048]
  const float* w_ff_in  = (const float*)d_in[5];   // [2048][8192]
  const float* b_ff_in  = (const float*)d_in[6];   // [8192]
  const float* w_ff_out = (const float*)d_in[7];   // [8192][2048]
  const float* b_ff_out = (const float*)d_in[8];   // [2048]
  float* out = (float*)d_out;

  char* ws = (char*)d_ws;
  bf16_t* wqkvT   = (bf16_t*)(ws);                  // [6144][2048]; dead after qkv GEMM
  bf16_t* waoT    = (bf16_t*)(ws + 25165824);       // [2048][2048]
  bf16_t* wffinT  = (bf16_t*)(ws + 33554432);       // [8192][2048]
  bf16_t* wffoutT = (bf16_t*)(ws + 67108864);       // [2048][8192]
  bf16_t* h       = (bf16_t*)(ws + 100663296);      // [2048][2048]
  bf16_t* qhb     = (bf16_t*)(ws + 109051904);      // [16][2048][128]
  bf16_t* khb     = (bf16_t*)(ws + 117440512);
  bf16_t* vTb     = (bf16_t*)(ws + 125829120);      // [16][128][2048]
  bf16_t* avb     = (bf16_t*)(ws + 134217728);      // [2048][2048]
  bf16_t* qkvb    = (bf16_t*)(ws + 142606336);      // [2048][6144]; later pab / ff1
  bf16_t* ff1b    = qkvb;
  bf16_t* pab     = qkvb;                           // attn_out bf16 partials 4x[2048][2048] = 33.6MB
  float*  pf      = (float*)(ws);                   // ff_out f32 partials 4x16.8MB = 67MB (dead weights)
  bf16_t* Opart   = (bf16_t*)(ws);                  // attn partials 3x[16][2048][128] bf16 (dead wqkvT)
  float2* mlpart  = (float2*)(ws + 167772160);      // 3x[16][2048] float2

  hipFuncSetAttribute((const void*)gemm2p<0>,  hipFuncAttributeMaxDynamicSharedMemorySize, 131072);
  hipFuncSetAttribute((const void*)gemm2p<8>,  hipFuncAttributeMaxDynamicSharedMemorySize, 131072);
  hipFuncSetAttribute((const void*)gemm2p<11>, hipFuncAttributeMaxDynamicSharedMemorySize, 131072);

  dim3 b256(256), b512(512);
  transpose_cvt<<<dim3(96, 32),  b256, 0, stream>>>(w_qkv,    wqkvT,   2048, 6144);
  transpose_cvt<<<dim3(32, 32),  b256, 0, stream>>>(w_ao,     waoT,    2048, 2048);
  transpose_cvt<<<dim3(128, 32), b256, 0, stream>>>(w_ff_in,  wffinT,  2048, 8192);
  transpose_cvt<<<dim3(32, 128), b256, 0, stream>>>(w_ff_out, wffoutT, 8192, 2048);
  ln_kernel<<<dim3(2048), b256, 0, stream>>>(x, ln_scale, ln_offset, h);

  gemm2p<8><<<dim3(24, 8, 1), b512, 131072, stream>>>(h, 2048, wqkvT, 2048,
      nullptr, nullptr, qkvb, 2048, 6144, 2048, 0);
  rope_kernel<<<dim3(2048, 16), dim3(128), 0, stream>>>(qkvb, qhb, khb, vTb);

  attn_kernel<<<dim3(16, 16, 3), b256, 0, stream>>>(qhb, khb, vTb, Opart, mlpart);
  attn_combine<<<dim3(2048), b256, 0, stream>>>(Opart, mlpart, avb);

  // attn_out: split-K=4 (K=512 each), bf16 partials in dead qkvb region -> 256 blocks
  gemm2p<8><<<dim3(8, 8, 4), b512, 131072, stream>>>(avb, 2048, waoT, 2048,
      nullptr, nullptr, pab, 2048, 2048, 512, (size_t)2048 * 2048);
  reduce4b<<<dim3(2048), b256, 0, stream>>>(pab, pab + 4194304, pab + 2 * 4194304,
      pab + 3 * 4194304, out, 4194304);

  gemm2p<11><<<dim3(32, 8, 1), b512, 131072, stream>>>(h, 2048, wffinT, 2048,
      b_ff_in, nullptr, ff1b, 2048, 8192, 2048, 0);

  // ff_out: split-K=4 (K=2048 each), f32 partials over dead weight region
  gemm2p<0><<<dim3(8, 8, 4), b512, 131072, stream>>>(ff1b, 8192, wffoutT, 8192,
      nullptr, pf, nullptr, 2048, 2048, 2048, (size_t)2048 * 2048);
  reduceP<4, true, true><<<dim3(4096), b256, 0, stream>>>(pf, pf + 4194304,
      pf + 2 * 4194304, pf + 3 * 4194304, b_ff_out, out, 4194304, 2047);
}

// Round 8
// 416.617 us; speedup vs baseline: 1.0937x; 1.0125x over previous
//
#include <hip/hip_runtime.h>
#include <hip/hip_bf16.h>

using bf16_t = __hip_bfloat16;
typedef __attribute__((ext_vector_type(8))) __bf16 bfrag;   // 8 bf16 = 4 VGPR (MFMA A/B operand)
typedef __attribute__((ext_vector_type(4))) float f32x4;    // MFMA C/D operand

#define MFMA16(a, b, c) __builtin_amdgcn_mfma_f32_16x16x32_bf16((a), (b), (c), 0, 0, 0)

__device__ __forceinline__ void gload_lds16(const void* g, void* l) {
  // async global->LDS, 16B/lane; LDS dest = wave-uniform base + lane*16
  __builtin_amdgcn_global_load_lds((const __attribute__((address_space(1))) void*)g,
                                   (__attribute__((address_space(3))) void*)l, 16, 0, 0);
}

__device__ __forceinline__ float bf2f(unsigned u) { return __uint_as_float(u << 16); }

// ---------- weight transpose + f32->bf16 convert: in[K][N] f32 -> out[N][K] bf16 ----------
__global__ __launch_bounds__(256) void transpose_cvt(const float* __restrict__ in,
    bf16_t* __restrict__ out, int K, int N) {
  __shared__ float t[64][65];
  const int n0 = blockIdx.x * 64, k0 = blockIdx.y * 64;
  const int tx = threadIdx.x & 15, ty = threadIdx.x >> 4;   // 16 x 16
#pragma unroll
  for (int i = 0; i < 4; ++i) {
    float4 v = *(const float4*)&in[(size_t)(k0 + i * 16 + ty) * N + n0 + tx * 4];
    t[i * 16 + ty][tx * 4 + 0] = v.x; t[i * 16 + ty][tx * 4 + 1] = v.y;
    t[i * 16 + ty][tx * 4 + 2] = v.z; t[i * 16 + ty][tx * 4 + 3] = v.w;
  }
  __syncthreads();
#pragma unroll
  for (int i = 0; i < 4; ++i) {
    const int n = i * 16 + ty;
    bf16_t w[4];
#pragma unroll
    for (int j = 0; j < 4; ++j) w[j] = bf16_t(t[tx * 4 + j][n]);
    *(uint2*)&out[(size_t)(n0 + n) * K + k0 + tx * 4] = *(const uint2*)w;
  }
}

// ---------- LayerNorm: x f32 [2048][2048] -> h bf16 ----------
__global__ __launch_bounds__(256) void ln_kernel(const float* __restrict__ x,
    const float* __restrict__ sc, const float* __restrict__ of, bf16_t* __restrict__ h) {
  __shared__ float red[8];
  const int n = blockIdx.x, tid = threadIdx.x;
  const float* xr = x + (size_t)n * 2048;
  float4 a = ((const float4*)xr)[tid * 2];
  float4 b = ((const float4*)xr)[tid * 2 + 1];
  float s = a.x + a.y + a.z + a.w + b.x + b.y + b.z + b.w;
  float q = a.x * a.x + a.y * a.y + a.z * a.z + a.w * a.w +
            b.x * b.x + b.y * b.y + b.z * b.z + b.w * b.w;
#pragma unroll
  for (int m = 32; m; m >>= 1) { s += __shfl_xor(s, m); q += __shfl_xor(q, m); }
  if ((tid & 63) == 0) { red[(tid >> 6) * 2] = s; red[(tid >> 6) * 2 + 1] = q; }
  __syncthreads();
  s = red[0] + red[2] + red[4] + red[6];
  q = red[1] + red[3] + red[5] + red[7];
  const float mu = s * (1.f / 2048.f);
  const float inv = rsqrtf(q * (1.f / 2048.f) - mu * mu + 1e-5f);
  const int base = tid * 8;
  float v[8] = {a.x, a.y, a.z, a.w, b.x, b.y, b.z, b.w};
  bf16_t* hr = h + (size_t)n * 2048 + base;
#pragma unroll
  for (int j = 0; j < 8; ++j) hr[j] = bf16_t((v[j] - mu) * inv * sc[base + j] + of[base + j]);
}

// ---------- m201-style 8-phase 256x256 GEMM: C = A[M][lda](bf16) * BT[N][ldb]^T ----------
// 8 phases / 2 K-tiles. Slots: A[d][h] = d*32768+h*16384, B = +65536. h = row-half.
// Phase reads (per wave): ph1 a0+b01(12), ph2 b23(4), ph3 a1(8), ph4 none; 16 MFMA each.
// Stage plan: ph1 SA(2k+1,0) ph2 SA(2k+1,1) ph3 SB(2k+2,0) ph4 SB(2k+2,1)
//             ph5 SA(2k+2,0) ph6 SA(2k+2,1) ph7 SB(2k+3,0) ph8 SB(2k+3,1)
// vmcnt(4) at ph4/ph8 only (2 loads x 2 younger stages); last iter drains 0.
// EPI bits: 1=+bias, 2=gelu, 8=store bf16 (else f32)
template <int EPI>
__global__ __launch_bounds__(512, 2) void gemm8p(
    const bf16_t* __restrict__ A, int lda, const bf16_t* __restrict__ BT, int ldb,
    const float* __restrict__ bias, float* __restrict__ Cf, bf16_t* __restrict__ Cb,
    int M, int N, int K, size_t splitStride) {
  extern __shared__ __align__(16) char lds[];   // 128 KiB
  const int tid = threadIdx.x, wid = tid >> 6, lane = tid & 63;
  const int lc = lane & 15, lg = lane >> 4;
  const int bm = blockIdx.y * 256, bn = blockIdx.x * 256;
  const int wr = wid >> 2, wc = wid & 3;              // 2M x 4N waves, each 128x64 out
  const int NT = K >> 6, niter = NT >> 1;             // NT even
  // staging geometry: lds off = slot + tid*16 + j*8192 -> row=tid>>3 (+64j), chunk pos=tid&7
  // swizzle: pos p holds global chunk p ^ (row&7)
  const int srow = tid >> 3;
  const int scol = (((tid & 7) ^ ((tid >> 3) & 7)) << 3);
  const bf16_t* Abase = A + (size_t)blockIdx.z * K + (size_t)(bm + srow) * lda + scol;
  const bf16_t* Bbase = BT + (size_t)blockIdx.z * K + (size_t)(bn + srow) * ldb + scol;
  auto SA = [&](int T, int h) {
    char* dst = lds + (T & 1) * 32768 + h * 16384 + wid * 1024;
    const bf16_t* src = Abase + (size_t)(h * 128) * lda + T * 64;
    gload_lds16(src, dst); gload_lds16(src + (size_t)64 * lda, dst + 8192);
  };
  auto SB = [&](int T, int h) {
    char* dst = lds + 65536 + (T & 1) * 32768 + h * 16384 + wid * 1024;
    const bf16_t* src = Bbase + (size_t)(h * 128) * ldb + T * 64;
    gload_lds16(src, dst); gload_lds16(src + (size_t)64 * ldb, dst + 8192);
  };
// fragment reads (local row 0..127 within the wave's half-slot)
#define FRA(d, row, kk) (*(const bfrag*)(lds + (d) * 32768 + wr * 16384 + (row) * 128 + \
    ((((kk) * 4 + lg) ^ ((row) & 7)) << 4)))
#define FRB(d, row, kk) (*(const bfrag*)(lds + 65536 + (d) * 32768 + (wc >> 1) * 16384 + \
    (row) * 128 + ((((kk) * 4 + lg) ^ ((row) & 7)) << 4)))
#define PHASE_SYNC() do { __builtin_amdgcn_s_barrier(); \
    asm volatile("s_waitcnt lgkmcnt(0)" ::: "memory"); \
    __builtin_amdgcn_sched_barrier(0); __builtin_amdgcn_s_setprio(1); } while (0)
#define PHASE_END() do { __builtin_amdgcn_s_setprio(0); __builtin_amdgcn_s_barrier(); } while (0)
#define PHASE_END_VM(lastf) do { __builtin_amdgcn_s_setprio(0); \
    if (lastf) asm volatile("s_waitcnt vmcnt(0)" ::: "memory"); \
    else       asm volatile("s_waitcnt vmcnt(4)" ::: "memory"); \
    __builtin_amdgcn_s_barrier(); } while (0)

  // prologue: tile0 all 4 halves + tile1 B halves
  SB(0, 0); SB(0, 1); SA(0, 0); SA(0, 1); SB(1, 0); SB(1, 1);
  asm volatile("s_waitcnt vmcnt(4)" ::: "memory");    // tile0 landed
  __builtin_amdgcn_s_barrier();

  f32x4 acc[8][4] = {};
  const int brl = (wc & 1) * 64 + lc;                 // B local row base (+n*16)

  for (int k = 0; k < niter; ++k) {
    const int T1 = 2 * k + 1, T2 = 2 * k + 2, T3 = 2 * k + 3;
    const bool last = (k == niter - 1);
    bfrag aq[4][2], b01[2][2], b23[2][2];
#pragma unroll 1
    for (int d = 0; d < 2; ++d) {                     // d=0: phases 1-4, d=1: phases 5-8
      // ---- phase 1/5: read a0-quad + b01; stage SA(T1,0) / SA(T2,0)
#pragma unroll
      for (int m = 0; m < 4; ++m)
#pragma unroll
        for (int kk = 0; kk < 2; ++kk) aq[m][kk] = FRA(d, m * 16 + lc, kk);
#pragma unroll
      for (int n = 0; n < 2; ++n)
#pragma unroll
        for (int kk = 0; kk < 2; ++kk) b01[n][kk] = FRB(d, brl + n * 16, kk);
      if (d == 0) SA(T1, 0); else if (!last) SA(T2, 0);
      PHASE_SYNC();
#pragma unroll
      for (int kk = 0; kk < 2; ++kk)
#pragma unroll
        for (int m = 0; m < 4; ++m) {
          acc[m][0] = MFMA16(aq[m][kk], b01[0][kk], acc[m][0]);
          acc[m][1] = MFMA16(aq[m][kk], b01[1][kk], acc[m][1]);
        }
      PHASE_END();
      // ---- phase 2/6: read b23; stage SA(T1,1) / SA(T2,1)
#pragma unroll
      for (int n = 0; n < 2; ++n)
#pragma unroll
        for (int kk = 0; kk < 2; ++kk) b23[n][kk] = FRB(d, brl + (n + 2) * 16, kk);
      if (d == 0) SA(T1, 1); else if (!last) SA(T2, 1);
      PHASE_SYNC();
#pragma unroll
      for (int kk = 0; kk < 2; ++kk)
#pragma unroll
        for (int m = 0; m < 4; ++m) {
          acc[m][2] = MFMA16(aq[m][kk], b23[0][kk], acc[m][2]);
          acc[m][3] = MFMA16(aq[m][kk], b23[1][kk], acc[m][3]);
        }
      PHASE_END();
      // ---- phase 3/7: read a1-quad; stage SB(T2,0) / SB(T3,0)
#pragma unroll
      for (int m = 0; m < 4; ++m)
#pragma unroll
        for (int kk = 0; kk < 2; ++kk) aq[m][kk] = FRA(d, (m + 4) * 16 + lc, kk);
      if (!last) { if (d == 0) SB(T2, 0); else SB(T3, 0); }
      PHASE_SYNC();
#pragma unroll
      for (int kk = 0; kk < 2; ++kk)
#pragma unroll
        for (int m = 0; m < 4; ++m) {
          acc[4 + m][2] = MFMA16(aq[m][kk], b23[0][kk], acc[4 + m][2]);
          acc[4 + m][3] = MFMA16(aq[m][kk], b23[1][kk], acc[4 + m][3]);
        }
      PHASE_END();
      // ---- phase 4/8: no reads; stage SB(T2,1) / SB(T3,1); counted vmcnt
      if (!last) { if (d == 0) SB(T2, 1); else SB(T3, 1); }
      PHASE_SYNC();
#pragma unroll
      for (int kk = 0; kk < 2; ++kk)
#pragma unroll
        for (int m = 0; m < 4; ++m) {
          acc[4 + m][0] = MFMA16(aq[m][kk], b01[0][kk], acc[4 + m][0]);
          acc[4 + m][1] = MFMA16(aq[m][kk], b01[1][kk], acc[4 + m][1]);
        }
      PHASE_END_VM(last);
    }
  }
#undef FRA
#undef FRB
#undef PHASE_SYNC
#undef PHASE_END
#undef PHASE_END_VM
  // ---- epilogue: per-wave LDS staging -> coalesced vector stores
  char* W = lds + wid * 16384;
  if (EPI & 8) {
    bf16_t* Wb = (bf16_t*)W;
    bf16_t* Cbz = Cb + (size_t)blockIdx.z * splitStride;
#pragma unroll
    for (int mc = 0; mc < 2; ++mc) {
#pragma unroll
      for (int m4 = 0; m4 < 4; ++m4) {
#pragma unroll
        for (int n = 0; n < 4; ++n) {
          const int col = bn + wc * 64 + n * 16 + lc;
          float bv = (EPI & 1) ? bias[col] : 0.f;
#pragma unroll
          for (int i = 0; i < 4; ++i) {
            float v = acc[mc * 4 + m4][n][i];
            if (EPI & 1) v += bv;
            if (EPI & 2) v = 0.5f * v * (1.f + tanhf(0.7978845608028654f * (v + 0.044715f * v * v * v)));
            Wb[(m4 * 16 + lg * 4 + i) * 72 + n * 16 + lc] = bf16_t(v);
          }
        }
      }
      asm volatile("s_waitcnt lgkmcnt(0)" ::: "memory");
      __builtin_amdgcn_sched_barrier(0);
#pragma unroll
      for (int p = 0; p < 8; ++p) {
        const int rl = p * 8 + (lane >> 3), j = lane & 7;
        uint4 v = *(const uint4*)&Wb[rl * 72 + j * 8];
        const int grow = bm + wr * 128 + mc * 64 + rl;
        const int gcol = bn + wc * 64 + j * 8;
        *(uint4*)&Cbz[(size_t)grow * N + gcol] = v;
      }
      asm volatile("s_waitcnt lgkmcnt(0)" ::: "memory");
      __builtin_amdgcn_sched_barrier(0);
    }
  } else {
    float* Wf = (float*)W;
    float* Cfz = Cf + (size_t)blockIdx.z * splitStride;
#pragma unroll
    for (int mc = 0; mc < 4; ++mc) {
#pragma unroll
      for (int m2 = 0; m2 < 2; ++m2) {
#pragma unroll
        for (int n = 0; n < 4; ++n) {
          const int col = bn + wc * 64 + n * 16 + lc;
          float bv = (EPI & 1) ? bias[col] : 0.f;
#pragma unroll
          for (int i = 0; i < 4; ++i) {
            float v = acc[mc * 2 + m2][n][i];
            if (EPI & 1) v += bv;
            if (EPI & 2) v = 0.5f * v * (1.f + tanhf(0.7978845608028654f * (v + 0.044715f * v * v * v)));
            Wf[(m2 * 16 + lg * 4 + i) * 72 + n * 16 + lc] = v;
          }
        }
      }
      asm volatile("s_waitcnt lgkmcnt(0)" ::: "memory");
      __builtin_amdgcn_sched_barrier(0);
#pragma unroll
      for (int p = 0; p < 8; ++p) {
        const int rl = p * 4 + (lane >> 4), j = lane & 15;
        float4 v = *(const float4*)&Wf[rl * 72 + j * 4];
        const int grow = bm + wr * 128 + mc * 32 + rl;
        const int gcol = bn + wc * 64 + j * 4;
        *(float4*)&Cfz[(size_t)grow * N + gcol] = v;
      }
      asm volatile("s_waitcnt lgkmcnt(0)" ::: "memory");
      __builtin_amdgcn_sched_barrier(0);
    }
  }
}

// ---------- split-K f32 partial reduction ----------
template <int NP, bool ADDIN, bool BIAS>
__global__ __launch_bounds__(256) void reduceP(const float* __restrict__ p0,
    const float* __restrict__ p1, const float* __restrict__ p2,
    const float* __restrict__ p3, const float* __restrict__ bias,
    float* __restrict__ out, int total, int colmask) {
  const int i = (blockIdx.x * 256 + threadIdx.x) * 4;
  if (i >= total) return;
  float4 v = *(const float4*)(p0 + i);
  float4 w = *(const float4*)(p1 + i);
  v.x += w.x; v.y += w.y; v.z += w.z; v.w += w.w;
  if (NP == 4) {
    float4 u = *(const float4*)(p2 + i);
    float4 z = *(const float4*)(p3 + i);
    v.x += u.x + z.x; v.y += u.y + z.y; v.z += u.z + z.z; v.w += u.w + z.w;
  }
  if (BIAS) {
    float4 b = *(const float4*)(bias + (i & colmask));
    v.x += b.x; v.y += b.y; v.z += b.z; v.w += b.w;
  }
  if (ADDIN) {
    float4 o = *(const float4*)(out + i);
    v.x += o.x; v.y += o.y; v.z += o.z; v.w += o.w;
  }
  *(float4*)(out + i) = v;
}

// ---------- split-K bf16 partial reduction (4 parts) -> f32 out ----------
__global__ __launch_bounds__(256) void reduce4b(const bf16_t* __restrict__ p0,
    const bf16_t* __restrict__ p1, const bf16_t* __restrict__ p2,
    const bf16_t* __restrict__ p3, float* __restrict__ out, int total) {
  const int i = (blockIdx.x * 256 + threadIdx.x) * 8;
  if (i >= total) return;
  uint4 a0 = *(const uint4*)(p0 + i);
  uint4 a1 = *(const uint4*)(p1 + i);
  uint4 a2 = *(const uint4*)(p2 + i);
  uint4 a3 = *(const uint4*)(p3 + i);
  const unsigned* u0 = (const unsigned*)&a0;
  const unsigned* u1 = (const unsigned*)&a1;
  const unsigned* u2 = (const unsigned*)&a2;
  const unsigned* u3 = (const unsigned*)&a3;
  float r[8];
#pragma unroll
  for (int j = 0; j < 8; ++j) {
    const int w = j >> 1, sh = (j & 1) * 16;
    r[j] = bf2f((u0[w] >> sh) & 0xffffu) + bf2f((u1[w] >> sh) & 0xffffu) +
           bf2f((u2[w] >> sh) & 0xffffu) + bf2f((u3[w] >> sh) & 0xffffu);
  }
  *(float4*)(out + i) = make_float4(r[0], r[1], r[2], r[3]);
  *(float4*)(out + i + 4) = make_float4(r[4], r[5], r[6], r[7]);
}

// ---------- RoPE + head split ----------
__global__ __launch_bounds__(128) void rope_kernel(const bf16_t* __restrict__ qkv,
    bf16_t* __restrict__ qh, bf16_t* __restrict__ kh, bf16_t* __restrict__ vT) {
  const int n = blockIdx.x, hh = blockIdx.y;
  const int d = threadIdx.x;
  const int mp = hh >> 2, hi = hh & 3;
  const bf16_t* row = qkv + (size_t)n * 6144 + mp * 1536 + hi * 128;  // [q|v|k] each 512 per mp
  float q = __bfloat162float(row[d]);
  float k = __bfloat162float(row[1024 + d]);
  if (d < 64) {  // wave-uniform branch
    const float ang = (float)n * powf(10000.f, -(float)(d & ~1) / 64.f);
    const float sn = sinf(ang), cs = cosf(ang);
    const float qp = __shfl_xor(q, 1), kp = __shfl_xor(k, 1);
    if (d & 1) { q = q * cs + qp * sn; k = k * cs + kp * sn; }
    else       { q = q * cs - qp * sn; k = k * cs - kp * sn; }
  }
  qh[((size_t)hh * 2048 + n) * 128 + d] = bf16_t(q * 0.08838834764831845f); // 1/sqrt(128)
  kh[((size_t)hh * 2048 + n) * 128 + d] = bf16_t(k);
  vT[((size_t)hh * 128 + d) * 2048 + n] = row[512 + d];
}

// ---------- causal flash attention, pairs + KV-split(z=3), partial (O,m,l) output ----------
__global__ __launch_bounds__(256) void attn_kernel(const bf16_t* __restrict__ qh,
    const bf16_t* __restrict__ kh, const bf16_t* __restrict__ vT,
    bf16_t* __restrict__ Op, float2* __restrict__ ml) {
  __shared__ alignas(16) char Kbuf[2][16384];    // [kv 64][d 128] bf16, chunk ^= row&15
  __shared__ alignas(16) char Vbuf[2][16384];    // [d 128][kv 64] bf16, chunk ^= row&7
  __shared__ alignas(16) bf16_t Ps[4][16 * 72];  // per-wave P, stride 72
  const int p = blockIdx.x, h = blockIdx.y, z = blockIdx.z;
  const int tid = threadIdx.x, wid = tid >> 6, lane = tid & 63;
  const int lc = lane & 15, lg = lane >> 4;
  const int krow = wid * 4 + (lane >> 4);
  const int vrow = wid * 8 + (lane >> 3);

  auto stage = [&](int kv0, int d) {
#pragma unroll
    for (int i = 0; i < 4; ++i) {
      const int kr = i * 16 + krow;
      const int kch = (lane & 15) ^ (kr & 15);
      gload_lds16(kh + ((size_t)h * 2048 + kv0 + kr) * 128 + kch * 8,
                  Kbuf[d] + i * 4096 + wid * 1024);
      const int vr = i * 32 + vrow;
      const int vch = (lane & 7) ^ (vr & 7);
      gload_lds16(vT + ((size_t)h * 128 + vr) * 2048 + kv0 + vch * 8,
                  Vbuf[d] + i * 4096 + wid * 1024);
    }
  };
#define FRK(d, row, ch) (*(const bfrag*)(Kbuf[d] + (row) * 256 + (((ch) ^ ((row) & 15)) << 4)))
#define FRV(d, row, ch) (*(const bfrag*)(Vbuf[d] + (row) * 128 + (((ch) ^ ((row) & 7)) << 4)))

#pragma unroll 1
  for (int half = 0; half < 2; ++half) {
    const int qt = half ? (31 - p) : p;
    const int nkv = qt + 1;
    const int lo = (z * nkv) / 3, hi = ((z + 1) * nkv) / 3;
    const int nj = hi - lo;
    const int qr = qt * 64 + wid * 16;
    const bf16_t* Qb = qh + ((size_t)h * 2048 + qr) * 128;
    bfrag qf[4];
#pragma unroll
    for (int ks = 0; ks < 4; ++ks)
      qf[ks] = *(const bfrag*)&Qb[lc * 128 + ks * 32 + lg * 8];
    f32x4 O[8] = {};
    float mr[4] = {-1e30f, -1e30f, -1e30f, -1e30f};
    float lsum[4] = {0.f, 0.f, 0.f, 0.f};

    if (nj > 0) {
      stage(lo * 64, 0);
      asm volatile("s_waitcnt vmcnt(0)" ::: "memory");
      __builtin_amdgcn_s_barrier();
    }
#pragma unroll 1
    for (int j = 0; j < nj; ++j) {
      const int kt = lo + j, d = j & 1;
      const int kv0 = kt * 64;
      if (j + 1 < nj) stage(kv0 + 64, d ^ 1);  // overlap with compute
      f32x4 s[4];
#pragma unroll
      for (int c = 0; c < 4; ++c) {
        f32x4 a = {};
#pragma unroll
        for (int ks = 0; ks < 4; ++ks) {
          bfrag kf = FRK(d, c * 16 + lc, ks * 4 + lg);
          a = MFMA16(qf[ks], kf, a);
        }
        s[c] = a;
      }
      if (kt == qt) {  // diagonal tile: causal mask
#pragma unroll
        for (int c = 0; c < 4; ++c)
#pragma unroll
          for (int i = 0; i < 4; ++i)
            if (kv0 + c * 16 + lc > qr + lg * 4 + i) s[c][i] = -1e10f;
      }
      float pm[4];
#pragma unroll
      for (int i = 0; i < 4; ++i)
        pm[i] = fmaxf(fmaxf(s[0][i], s[1][i]), fmaxf(s[2][i], s[3][i]));
#pragma unroll
      for (int m = 1; m < 16; m <<= 1)
#pragma unroll
        for (int i = 0; i < 4; ++i) pm[i] = fmaxf(pm[i], __shfl_xor(pm[i], m));
      float al[4], rs[4];
#pragma unroll
      for (int i = 0; i < 4; ++i) {
        const float mn = fmaxf(mr[i], pm[i]);
        al[i] = __expf(mr[i] - mn);
        mr[i] = mn;
        rs[i] = 0.f;
      }
#pragma unroll
      for (int c = 0; c < 4; ++c)
#pragma unroll
        for (int i = 0; i < 4; ++i) {
          const float pv = __expf(s[c][i] - mr[i]);
          s[c][i] = pv; rs[i] += pv;
        }
#pragma unroll
      for (int m = 1; m < 16; m <<= 1)
#pragma unroll
        for (int i = 0; i < 4; ++i) rs[i] += __shfl_xor(rs[i], m);
#pragma unroll
      for (int i = 0; i < 4; ++i) lsum[i] = lsum[i] * al[i] + rs[i];
#pragma unroll
      for (int n = 0; n < 8; ++n)
#pragma unroll
        for (int i = 0; i < 4; ++i) O[n][i] *= al[i];
#pragma unroll
      for (int c = 0; c < 4; ++c)
#pragma unroll
        for (int i = 0; i < 4; ++i)
          Ps[wid][(lg * 4 + i) * 72 + c * 16 + lc] = bf16_t(s[c][i]);
#pragma unroll
      for (int k2 = 0; k2 < 2; ++k2) {
        bfrag pf = *(const bfrag*)((const char*)&Ps[wid][0] + lc * 144 + k2 * 64 + lg * 16);
#pragma unroll
        for (int n = 0; n < 8; ++n) {
          bfrag vf = FRV(d, n * 16 + lc, k2 * 4 + lg);
          O[n] = MFMA16(pf, vf, O[n]);
        }
      }
      if (j + 1 < nj) asm volatile("s_waitcnt vmcnt(0)" ::: "memory");
      asm volatile("s_waitcnt lgkmcnt(0)" ::: "memory");
      __builtin_amdgcn_s_barrier();
    }
    const size_t rb = (size_t)(z * 16 + h) * 2048 + qr;
#pragma unroll
    for (int n = 0; n < 8; ++n)
#pragma unroll
      for (int i = 0; i < 4; ++i)
        Op[(rb + lg * 4 + i) * 128 + n * 16 + lc] = bf16_t(O[n][i]);
    if (lc == 0) {
#pragma unroll
      for (int i = 0; i < 4; ++i)
        ml[rb + lg * 4 + i] = make_float2(mr[i], lsum[i]);
    }
    __builtin_amdgcn_s_barrier();
  }
#undef FRK
#undef FRV
}

// ---------- combine z=3 attention partials -> av bf16 [2048][2048] ----------
__global__ __launch_bounds__(256) void attn_combine(const bf16_t* __restrict__ Op,
    const float2* __restrict__ ml, bf16_t* __restrict__ av) {
  const int idx = blockIdx.x * 256 + threadIdx.x;
  const int t = idx & 15, hr = idx >> 4;
  const int ZS = 16 * 2048;
  const size_t ZO = (size_t)ZS * 128;
  const float2 m0 = ml[hr], m1 = ml[ZS + hr], m2 = ml[2 * ZS + hr];
  const float M = fmaxf(fmaxf(m0.x, m1.x), m2.x);
  const float w0 = __expf(m0.x - M), w1 = __expf(m1.x - M), w2 = __expf(m2.x - M);
  const float inv = 1.f / (w0 * m0.y + w1 * m1.y + w2 * m2.y);
  const bf16_t* p0 = Op + (size_t)hr * 128 + t * 8;
  uint4 a0 = *(const uint4*)p0;
  uint4 a1 = *(const uint4*)(p0 + ZO);
  uint4 a2 = *(const uint4*)(p0 + 2 * ZO);
  const unsigned* u0 = (const unsigned*)&a0;
  const unsigned* u1 = (const unsigned*)&a1;
  const unsigned* u2 = (const unsigned*)&a2;
  bf16_t ov[8];
#pragma unroll
  for (int j = 0; j < 8; ++j) {
    const int w = j >> 1, sh = (j & 1) * 16;
    ov[j] = bf16_t((w0 * bf2f((u0[w] >> sh) & 0xffffu) +
                    w1 * bf2f((u1[w] >> sh) & 0xffffu) +
                    w2 * bf2f((u2[w] >> sh) & 0xffffu)) * inv);
  }
  const int row = hr & 2047, hh = hr >> 11;
  *(uint4*)(av + (size_t)row * 2048 + hh * 128 + t * 8) = *(const uint4*)ov;
}

extern "C" void kernel_launch(void* const* d_in, const int* in_sizes, int n_in,
                              void* d_out, int out_size, void* d_ws, size_t ws_size,
                              hipStream_t stream) {
  const float* x        = (const float*)d_in[0];
  const float* ln_scale = (const float*)d_in[1];
  const float* ln_offset= (const float*)d_in[2];
  const float* w_qkv    = (const float*)d_in[3];   // [2048][6144]
  const float* w_ao     = (const float*)d_in[4];   // [2048][2048]
  const float* w_ff_in  = (const float*)d_in[5];   // [2048][8192]
  const float* b_ff_in  = (const float*)d_in[6];   // [8192]
  const float* w_ff_out = (const float*)d_in[7];   // [8192][2048]
  const float* b_ff_out = (const float*)d_in[8];   // [2048]
  float* out = (float*)d_out;

  char* ws = (char*)d_ws;
  bf16_t* wqkvT   = (bf16_t*)(ws);                  // [6144][2048]; dead after qkv GEMM
  bf16_t* waoT    = (bf16_t*)(ws + 25165824);       // [2048][2048]
  bf16_t* wffinT  = (bf16_t*)(ws + 33554432);       // [8192][2048]
  bf16_t* wffoutT = (bf16_t*)(ws + 67108864);       // [2048][8192]
  bf16_t* h       = (bf16_t*)(ws + 100663296);      // [2048][2048]
  bf16_t* qhb     = (bf16_t*)(ws + 109051904);      // [16][2048][128]
  bf16_t* khb     = (bf16_t*)(ws + 117440512);
  bf16_t* vTb     = (bf16_t*)(ws + 125829120);      // [16][128][2048]
  bf16_t* avb     = (bf16_t*)(ws + 134217728);      // [2048][2048]
  bf16_t* qkvb    = (bf16_t*)(ws + 142606336);      // [2048][6144]; later pab / ff1
  bf16_t* ff1b    = qkvb;
  bf16_t* pab     = qkvb;                           // attn_out bf16 partials 4x[2048][2048]
  float*  pf      = (float*)(ws);                   // ff_out f32 partials (dead weights)
  bf16_t* Opart   = (bf16_t*)(ws);                  // attn partials 3x[16][2048][128] bf16
  float2* mlpart  = (float2*)(ws + 167772160);      // 3x[16][2048] float2

  hipFuncSetAttribute((const void*)gemm8p<0>,  hipFuncAttributeMaxDynamicSharedMemorySize, 131072);
  hipFuncSetAttribute((const void*)gemm8p<8>,  hipFuncAttributeMaxDynamicSharedMemorySize, 131072);
  hipFuncSetAttribute((const void*)gemm8p<11>, hipFuncAttributeMaxDynamicSharedMemorySize, 131072);

  dim3 b256(256), b512(512);
  transpose_cvt<<<dim3(96, 32),  b256, 0, stream>>>(w_qkv,    wqkvT,   2048, 6144);
  transpose_cvt<<<dim3(32, 32),  b256, 0, stream>>>(w_ao,     waoT,    2048, 2048);
  transpose_cvt<<<dim3(128, 32), b256, 0, stream>>>(w_ff_in,  wffinT,  2048, 8192);
  transpose_cvt<<<dim3(32, 128), b256, 0, stream>>>(w_ff_out, wffoutT, 8192, 2048);
  ln_kernel<<<dim3(2048), b256, 0, stream>>>(x, ln_scale, ln_offset, h);

  gemm8p<8><<<dim3(24, 8, 1), b512, 131072, stream>>>(h, 2048, wqkvT, 2048,
      nullptr, nullptr, qkvb, 2048, 6144, 2048, 0);
  rope_kernel<<<dim3(2048, 16), dim3(128), 0, stream>>>(qkvb, qhb, khb, vTb);

  attn_kernel<<<dim3(16, 16, 3), b256, 0, stream>>>(qhb, khb, vTb, Opart, mlpart);
  attn_combine<<<dim3(2048), b256, 0, stream>>>(Opart, mlpart, avb);

  // attn_out: split-K=4 (K=512 each), bf16 partials in dead qkvb region
  gemm8p<8><<<dim3(8, 8, 4), b512, 131072, stream>>>(avb, 2048, waoT, 2048,
      nullptr, nullptr, pab, 2048, 2048, 512, (size_t)2048 * 2048);
  reduce4b<<<dim3(2048), b256, 0, stream>>>(pab, pab + 4194304, pab + 2 * 4194304,
      pab + 3 * 4194304, out, 4194304);

  gemm8p<11><<<dim3(32, 8, 1), b512, 131072, stream>>>(h, 2048, wffinT, 2048,
      b_ff_in, nullptr, ff1b, 2048, 8192, 2048, 0);

  // ff_out: split-K=4 (K=2048 each), f32 partials over dead weight region
  gemm8p<0><<<dim3(8, 8, 4), b512, 131072, stream>>>(ff1b, 8192, wffoutT, 8192,
      nullptr, pf, nullptr, 2048, 2048, 2048, (size_t)2048 * 2048);
  reduceP<4, true, true><<<dim3(4096), b256, 0, stream>>>(pf, pf + 4194304,
      pf + 2 * 4194304, pf + 3 * 4194304, b_ff_out, out, 4194304, 2047);
}